// Round 10
// baseline (2447.640 us; speedup 1.0000x reference)
//
#include <hip/hip_runtime.h>

#define FULL_PER_IMG 65472
#define SEL_PER_IMG  3960
#define BBOX_CLIP    4.135166556742356f

__device__ __forceinline__ unsigned int sortkey(float f){
  unsigned int u = __float_as_uint(f);
  return (u & 0x80000000u) ? ~u : (u | 0x80000000u);
}

// conv_w [co][ci][3][3] -> wp [ci][tap][co]  (lane-coalesced by co)
__global__ __launch_bounds__(256) void repack_w(const float* __restrict__ src,
                                                float* __restrict__ dst){
  int idx = blockIdx.x*256 + threadIdx.x;     // 589824 total
  if (idx >= 589824) return;
  int co = idx & 255;
  int kt = idx >> 8;          // ci*9+tap
  int ci = kt / 9, tap = kt % 9;
  dst[idx] = src[co*2304 + ci*9 + tap];
}

#define CHBUF 1536   // floats per stage buffer (TX=8: 32*4*12)

// 2-row x TX tile per block (R8 structure, VGPR 56 verified) + weight
// prefetch one ci ahead (wv0/wv1 ping-pong): ci+1's 9 loads issue before
// ci's 144 FMAs, hiding L2 latency under FMA issue. Per accumulator the
// order stays ci asc, ky asc, kx asc, p -> bit-identical to prior rounds.
template<int TX, int H, int NBX>
__device__ void conv_level(int lb,
    const float* __restrict__ f, int strd, float asize, int full_off, float lvl,
    const float* __restrict__ wp, const float* __restrict__ conv_b,
    const float* __restrict__ cls_w, const float* __restrict__ cls_b,
    const float* __restrict__ bbox_w, const float* __restrict__ bbox_b,
    float* __restrict__ A_score, float* __restrict__ A_masked, float* __restrict__ A_boxoff,
    float* lds_stage, float* lds_t, float (*s_out)[16])
{
  constexpr int W    = H;
  constexpr int NBY  = H/2;
  constexpr int P    = 2*TX;            // outputs per block
  constexpr int ROWW = TX + 4;          // window x0-1 .. x0+TX+2
  constexpr int CIST = 4*ROWW;          // 4 input rows per ci in stage
  constexpr int CHFL = 32*CIST;         // floats per 32-ci chunk
  constexpr int NSTG = (CHFL + 255)/256;

  const int xb = lb % NBX;
  const int yb = (lb / NBX) % NBY;
  const int n  = lb / (NBX*NBY);
  const int x0 = xb * TX;
  const int y0 = yb * 2;
  const int co = threadIdx.x;
  const float* Fn = f + (size_t)n*256*H*W;

  float acc[2][TX];
  #pragma unroll
  for (int o=0;o<2;o++)
    #pragma unroll
    for (int p=0;p<TX;p++) acc[o][p] = conv_b[co];

  // hoisted staging offsets: soff[k] is chunk-relative element offset, -1 = OOB zero
  int soff[NSTG];
  #pragma unroll
  for (int k=0;k<NSTG;k++){
    const int e  = co + k*256;
    const int cl = e / CIST;
    const int rem = e - cl*CIST;
    const int r  = rem / ROWW;
    const int j  = rem - r*ROWW;
    const int yg = y0 - 1 + r, xg = x0 - 1 + j;
    soff[k] = (e < CHFL && yg>=0 && yg<H && xg>=0 && xg<W)
            ? (cl*H + yg)*W + xg : -1;
  }

  // load + immediately store to LDS (short live ranges -> no spill)
#define STAGE(CB, BUF) do {                                                  \
    const float* Fb_ = Fn + (size_t)(CB)*H*W;                                \
    float st_[NSTG];                                                         \
    _Pragma("unroll")                                                        \
    for (int k=0;k<NSTG;k++)                                                 \
      st_[k] = (soff[k] >= 0) ? Fb_[soff[k]] : 0.f;                          \
    _Pragma("unroll")                                                        \
    for (int k=0;k<NSTG;k++){                                                \
      const int e = co + k*256;                                              \
      if (e < CHFL) (BUF)[e] = st_[k];                                       \
    }                                                                        \
  } while(0)

#define LOADWV(CI, WV) do {                                                  \
    const float* wrow_ = wp + (size_t)(CI)*2304 + co;                        \
    _Pragma("unroll")                                                        \
    for (int t=0;t<9;t++) WV[t] = wrow_[t*256];                              \
  } while(0)

  // one ci: 4 input rows; row r -> acc[0](ky=r) and acc[1](ky=r-1)
#define CIFMA(SB, CL, WV) do {                                               \
    const float* bp_ = (SB) + (CL)*CIST;                                     \
    _Pragma("unroll")                                                        \
    for (int r=0;r<4;r++){                                                   \
      float rw_[ROWW];                                                       \
      _Pragma("unroll")                                                      \
      for (int q=0;q<ROWW/4;q++){                                            \
        float4 v_ = *(const float4*)(bp_ + r*ROWW + 4*q);                    \
        rw_[4*q+0]=v_.x; rw_[4*q+1]=v_.y;                                    \
        rw_[4*q+2]=v_.z; rw_[4*q+3]=v_.w;                                    \
      }                                                                      \
      if (r <= 2){                                                           \
        _Pragma("unroll")                                                    \
        for (int kx=0;kx<3;kx++){                                            \
          const float w_ = WV[r*3+kx];                                       \
          _Pragma("unroll")                                                  \
          for (int p=0;p<TX;p++) acc[0][p] = fmaf(w_, rw_[p+kx], acc[0][p]); \
        }                                                                    \
      }                                                                      \
      if (r >= 1){                                                           \
        _Pragma("unroll")                                                    \
        for (int kx=0;kx<3;kx++){                                            \
          const float w_ = WV[(r-1)*3+kx];                                   \
          _Pragma("unroll")                                                  \
          for (int p=0;p<TX;p++) acc[1][p] = fmaf(w_, rw_[p+kx], acc[1][p]); \
        }                                                                    \
      }                                                                      \
    }                                                                        \
  } while(0)

  STAGE(0, lds_stage);
  __syncthreads();

  float wv0[9], wv1[9];
  LOADWV(0, wv0);

  for (int ch=0; ch<8; ++ch){
    const float* sb = lds_stage + (ch&1)*CHBUF;
    for (int cl=0; cl<32; cl+=2){
      const int ci = ch*32 + cl;
      LOADWV(ci+1, wv1);                 // prefetch: issue before ci's FMAs
      CIFMA(sb, cl,   wv0);
      LOADWV((ci+2<256)?(ci+2):255, wv0);
      CIFMA(sb, cl+1, wv1);
    }
    if (ch<7){
      STAGE((ch+1)*32, lds_stage + ((ch+1)&1)*CHBUF);
      __syncthreads();
    }
  }
#undef STAGE
#undef LOADWV
#undef CIFMA

  // t tile -> LDS (stride 260: float4-aligned, 2-way-max banks)
  #pragma unroll
  for (int o=0;o<2;o++)
    #pragma unroll
    for (int p=0;p<TX;p++) lds_t[(o*TX+p)*260+co] = fmaxf(acc[o][p], 0.f);
  __syncthreads();

  {
    const int p = threadIdx.x % P;
    const int o = threadIdx.x / P;
    if (o < 15){
      const float* w1 = (o<3) ? (cls_w + o*256) : (bbox_w + (o-3)*256);
      float s = (o<3) ? cls_b[o] : bbox_b[o-3];
      const float4* wl = (const float4*)w1;
      const float4* tl = (const float4*)(lds_t + p*260);
      #pragma unroll 8
      for (int c=0;c<64;c++){
        float4 a = wl[c], b = tl[c];
        s += a.x*b.x + a.y*b.y + a.z*b.z + a.w*b.w;
      }
      s_out[o][p] = s;
    }
  }
  __syncthreads();

  if (threadIdx.x < 3*P){
    const int p = threadIdx.x / 3;
    const int a = threadIdx.x % 3;
    const int px = p % TX;
    const int yo = y0 + p / TX;
    float sraw = s_out[a][p];
    float dx = s_out[3+a*4+0][p];
    float dy = s_out[3+a*4+1][p];
    float dw = fminf(s_out[3+a*4+2][p], BBOX_CLIP);
    float dh = fminf(s_out[3+a*4+3][p], BBOX_CLIP);
    float ratio = (a==0)?0.5f:((a==1)?1.0f:2.0f);
    float hr = sqrtf(ratio);
    float wh2 = rintf(asize / hr * 0.5f);   // round-half-even == np.round (no .5 cases)
    float hh2 = rintf(asize * hr * 0.5f);
    float w = 2.f*wh2, h = 2.f*hh2;
    float cx = (float)((x0+px)*strd);
    float cy = (float)(yo*strd);
    float pcx = dx*w + cx, pcy = dy*h + cy;
    float pw = expf(dw)*w, ph = expf(dh)*h;
    float x1 = pcx - 0.5f*pw, y1 = pcy - 0.5f*ph;
    float x2 = pcx + 0.5f*pw, y2 = pcy + 0.5f*ph;
    x1 = fminf(fmaxf(x1,0.f),512.f); y1 = fminf(fmaxf(y1,0.f),512.f);
    x2 = fminf(fmaxf(x2,0.f),512.f); y2 = fminf(fmaxf(y2,0.f),512.f);
    bool valid = ((x2-x1) >= 1e-3f) && ((y2-y1) >= 1e-3f);
    float prob = 1.f/(1.f+expf(-sraw));
    float masked = valid ? prob : -1.f;
    float off = lvl*513.f;
    size_t gi = (size_t)n*FULL_PER_IMG + full_off + ((yo*W + (x0+px))*3 + a);
    A_score[gi]  = sraw;
    A_masked[gi] = masked;
    float4 bo; bo.x=x1+off; bo.y=y1+off; bo.z=x2+off; bo.w=y2+off;
    *(float4*)(A_boxoff + gi*4) = bo;
  }
}

// All 5 levels in ONE dispatch: 4096+1024+256+128+32 = 5536 blocks.
__global__ __launch_bounds__(256)
void conv_all(
    const float* __restrict__ f0, const float* __restrict__ f1,
    const float* __restrict__ f2, const float* __restrict__ f3,
    const float* __restrict__ f4,
    const float* __restrict__ wp, const float* __restrict__ conv_b,
    const float* __restrict__ cls_w, const float* __restrict__ cls_b,
    const float* __restrict__ bbox_w, const float* __restrict__ bbox_b,
    float* __restrict__ A_score, float* __restrict__ A_masked, float* __restrict__ A_boxoff)
{
  __shared__ float lds_stage[2*CHBUF];
  __shared__ float lds_t[16*260];
  __shared__ float s_out[15][16];
  const int b = blockIdx.x;
  if (b < 4096)
    conv_level< 8,128,16>(b,      f0,  4,  16.f,     0, 0.f, wp, conv_b, cls_w, cls_b, bbox_w, bbox_b, A_score, A_masked, A_boxoff, lds_stage, lds_t, s_out);
  else if (b < 5120)
    conv_level< 8, 64, 8>(b-4096, f1,  8,  32.f, 49152, 1.f, wp, conv_b, cls_w, cls_b, bbox_w, bbox_b, A_score, A_masked, A_boxoff, lds_stage, lds_t, s_out);
  else if (b < 5376)
    conv_level< 8, 32, 4>(b-5120, f2, 16,  64.f, 61440, 2.f, wp, conv_b, cls_w, cls_b, bbox_w, bbox_b, A_score, A_masked, A_boxoff, lds_stage, lds_t, s_out);
  else if (b < 5504)
    conv_level< 4, 16, 4>(b-5376, f3, 32, 128.f, 64512, 3.f, wp, conv_b, cls_w, cls_b, bbox_w, bbox_b, A_score, A_masked, A_boxoff, lds_stage, lds_t, s_out);
  else
    conv_level< 4,  8, 2>(b-5504, f4, 64, 256.f, 65280, 4.f, wp, conv_b, cls_w, cls_b, bbox_w, bbox_b, A_score, A_masked, A_boxoff, lds_stage, lds_t, s_out);
}

// blocks 0..11: exact top-1000 radix select per (img, lvl 0..2)
// blocks 12..15: lvl3+lvl4 passthrough copy (one block per image)
__global__ __launch_bounds__(1024) void select_kernel(
    const float* __restrict__ A_score, const float* __restrict__ A_masked,
    const float* __restrict__ A_boxoff,
    float* __restrict__ C_masked, float* __restrict__ C_boxoff)
{
  const int b = blockIdx.x;
  const int tid = threadIdx.x;
  if (b >= 12){
    const int n = b - 12;
    if (tid < 960){
      size_t gF = (size_t)n*FULL_PER_IMG + 64512 + tid;
      size_t gS = (size_t)n*SEL_PER_IMG  + 3000 + tid;
      C_masked[gS] = A_masked[gF];
      *(float4*)(C_boxoff + gS*4) = *(const float4*)(A_boxoff + gF*4);
    }
    return;
  }
  const int n = b / 3, lvl = b % 3;
  const int HWAs[3]  = {49152, 12288, 3072};
  const int FOFF[3]  = {0, 49152, 61440};
  const int HWA = HWAs[lvl];
  const size_t baseF = (size_t)n*FULL_PER_IMG + FOFF[lvl];
  const size_t baseS = (size_t)n*SEL_PER_IMG + lvl*1000;
  const int k = 1000;

  __shared__ unsigned int hist[256];
  __shared__ unsigned int sh_prefix, sh_krem, sh_c0, sh_c1, sh_above;
  if (tid==0){ sh_prefix=0u; sh_krem=(unsigned)k; }
  __syncthreads();

  for (int pass=3; pass>=0; pass--){
    if (tid < 256) hist[tid]=0u;
    __syncthreads();
    unsigned int pfx = sh_prefix;
    for (int i=tid;i<HWA;i+=1024){
      unsigned int u = sortkey(A_score[baseF+i]);
      if (pass==3 || (u >> ((pass+1)*8)) == pfx)
        atomicAdd(&hist[(u>>(pass*8)) & 255u], 1u);
    }
    __syncthreads();
    if (tid==0){
      unsigned int krem = sh_krem, accum = 0u; int chosen = 0;
      for (int bb=255; bb>=0; bb--){
        if (accum + hist[bb] >= krem){ chosen = bb; break; }
        accum += hist[bb];
      }
      sh_krem   = krem - accum;
      sh_prefix = (pfx<<8) | (unsigned)chosen;
    }
    __syncthreads();
  }
  const unsigned int T = sh_prefix;
  if (tid==0){ sh_c0=0u; sh_c1=0u; sh_above = (unsigned)k - sh_krem; }
  __syncthreads();
  const unsigned int nAbove = sh_above, need = sh_krem;

  for (int i=tid;i<HWA;i+=1024){
    unsigned int u = sortkey(A_score[baseF+i]);
    int pos = -1;
    if (u > T) pos = (int)atomicAdd(&sh_c0,1u);
    else if (u == T){
      unsigned int t = atomicAdd(&sh_c1,1u);
      if (t < need) pos = (int)(nAbove + t);
    }
    if (pos >= 0){
      C_masked[baseS+pos] = A_masked[baseF+i];
      *(float4*)(C_boxoff + (baseS+pos)*4) = *(const float4*)(A_boxoff + (baseF+i)*4);
    }
  }
}

// 256 threads, 16 consecutive candidates/thread, ONE barrier per pick:
// per-wave winner (v, idx, box) published in double-buffered LDS slots.
__global__ __launch_bounds__(256) void nms_kernel(
    const float* __restrict__ C_masked, const float* __restrict__ C_boxoff,
    float* __restrict__ out_b, float* __restrict__ out_s)
{
  const int n = blockIdx.x, tid = threadIdx.x;
  float  s[16];
  float4 b[16];
  #pragma unroll
  for (int j=0;j<16;j++){
    int i = tid*16 + j;
    if (i < SEL_PER_IMG){
      s[j] = C_masked[(size_t)n*SEL_PER_IMG + i];
      b[j] = *(const float4*)(C_boxoff + ((size_t)n*SEL_PER_IMG + i)*4);
    } else { s[j] = -2.f; b[j] = make_float4(0.f,0.f,0.f,0.f); }
  }
  __shared__ float wslot[2][4][6];   // [phase][wave][v, idx, x1,y1,x2,y2]

  for (int step=0; step<300; step++){
    float v = -3.f; int bi = 1<<30;
    #pragma unroll
    for (int j=0;j<16;j++){
      if (s[j] > v){ v = s[j]; bi = tid*16 + j; }    // strictly > : lowest idx on tie
    }
    #pragma unroll
    for (int m=32; m>=1; m>>=1){
      float ov = __shfl_xor(v, m); int oi = __shfl_xor(bi, m);
      if (ov > v || (ov == v && oi < bi)){ v = ov; bi = oi; }
    }
    // owning lane publishes its wave's winner (static-indexed scan, rule #20)
    float (*slot)[6] = wslot[step & 1];
    #pragma unroll
    for (int j=0;j<16;j++){
      if (tid*16 + j == bi){
        const int w = tid >> 6;
        slot[w][0] = v; slot[w][1] = __int_as_float(bi);
        slot[w][2] = b[j].x; slot[w][3] = b[j].y;
        slot[w][4] = b[j].z; slot[w][5] = b[j].w;
      }
    }
    __syncthreads();                                  // the only barrier
    float bv = slot[0][0]; int bidx = __float_as_int(slot[0][1]);
    float b0 = slot[0][2], b1 = slot[0][3], b2 = slot[0][4], b3 = slot[0][5];
    #pragma unroll
    for (int q=1;q<4;q++){
      float qv = slot[q][0]; int qi = __float_as_int(slot[q][1]);
      bool take = (qv > bv) || (qv == bv && qi < bidx);
      if (take){
        bv = qv; bidx = qi;
        b0 = slot[q][2]; b1 = slot[q][3]; b2 = slot[q][4]; b3 = slot[q][5];
      }
    }
    if (bv <= -0.5f) break;              // uniform; rest of d_out already zero
    float area_i = (b2-b0)*(b3-b1);
    #pragma unroll
    for (int j=0;j<16;j++){
      float xx1 = fmaxf(b0, b[j].x), yy1 = fmaxf(b1, b[j].y);
      float xx2 = fminf(b2, b[j].z), yy2 = fminf(b3, b[j].w);
      float iw = fmaxf(xx2-xx1, 0.f), ih = fmaxf(yy2-yy1, 0.f);
      float inter = iw*ih;
      float aj = (b[j].z-b[j].x)*(b[j].w-b[j].y);
      float iou = inter / fmaxf(area_i + aj - inter, 1e-9f);
      if (iou > 0.7f) s[j] = -1.f;
    }
    if (tid == 0){
      int lvl = (bidx<1000)?0:((bidx<2000)?1:((bidx<3000)?2:((bidx<3768)?3:4)));
      float off = (float)lvl * 513.f;
      size_t ob = ((size_t)n*300 + step)*4;
      out_b[ob+0]=b0-off; out_b[ob+1]=b1-off; out_b[ob+2]=b2-off; out_b[ob+3]=b3-off;
      out_s[(size_t)n*300 + step] = bv;
    }
  }
}

extern "C" void kernel_launch(void* const* d_in, const int* in_sizes, int n_in,
                              void* d_out, int out_size, void* d_ws, size_t ws_size,
                              hipStream_t stream) {
  (void)in_sizes; (void)n_in; (void)ws_size;
  const float* f0     = (const float*)d_in[1];
  const float* f1     = (const float*)d_in[2];
  const float* f2     = (const float*)d_in[3];
  const float* f3     = (const float*)d_in[4];
  const float* f4     = (const float*)d_in[5];
  const float* conv_w = (const float*)d_in[6];
  const float* conv_b = (const float*)d_in[7];
  const float* cls_w  = (const float*)d_in[8];
  const float* cls_b  = (const float*)d_in[9];
  const float* bbox_w = (const float*)d_in[10];
  const float* bbox_b = (const float*)d_in[11];

  float* ws       = (float*)d_ws;
  float* wp       = ws;                       // 589824
  float* A_score  = wp       + 589824;        // 261888
  float* A_masked = A_score  + 261888;        // 261888
  float* A_boxoff = A_masked + 261888;        // 1047552
  float* C_masked = A_boxoff + 1047552;       // 15840
  float* C_boxoff = C_masked + 15840;         // 63360

  float* out_b = (float*)d_out;               // [4][300][4]
  float* out_s = out_b + 4800;                // [4][300]

  hipMemsetAsync(d_out, 0, (size_t)out_size*sizeof(float), stream);

  repack_w<<<2304, 256, 0, stream>>>(conv_w, wp);

  conv_all<<<5536, 256, 0, stream>>>(f0, f1, f2, f3, f4,
      wp, conv_b, cls_w, cls_b, bbox_w, bbox_b, A_score, A_masked, A_boxoff);

  select_kernel<<<16, 1024, 0, stream>>>(A_score, A_masked, A_boxoff, C_masked, C_boxoff);
  nms_kernel<<<4, 256, 0, stream>>>(C_masked, C_boxoff, out_b, out_s);
}

// Round 11
// 2192.909 us; speedup vs baseline: 1.1162x; 1.1162x over previous
//
#include <hip/hip_runtime.h>

#define FULL_PER_IMG 65472
#define SEL_PER_IMG  3960
#define BBOX_CLIP    4.135166556742356f

__device__ __forceinline__ unsigned int sortkey(float f){
  unsigned int u = __float_as_uint(f);
  return (u & 0x80000000u) ? ~u : (u | 0x80000000u);
}

// conv_w [co][ci][3][3] -> wp [ci][tap][co]  (lane-coalesced by co)
__global__ __launch_bounds__(256) void repack_w(const float* __restrict__ src,
                                                float* __restrict__ dst){
  int idx = blockIdx.x*256 + threadIdx.x;     // 589824 total
  if (idx >= 589824) return;
  int co = idx & 255;
  int kt = idx >> 8;          // ci*9+tap
  int ci = kt / 9, tap = kt % 9;
  dst[idx] = src[co*2304 + ci*9 + tap];
}

#define CHBUF 1536   // floats per stage buffer (TX=8: 32*4*12)
#define SMEMF 4160   // union: max(2*CHBUF=3072, lds_t 16*260=4160) floats

// R8 conv structure (VGPR 56, 1457us verified) + LDS union: the staging
// double-buffer and the epilogue lds_t tile share one smem block (stage is
// dead before lds_t is written; one extra barrier guards the overwrite).
// LDS 30.2KB -> 17.7KB: occupancy cap rises 5 -> 8 blocks/CU.
// Per accumulator order stays ci asc, ky asc, kx asc, p -> bit-identical.
template<int TX, int H, int NBX>
__device__ void conv_level(int lb,
    const float* __restrict__ f, int strd, float asize, int full_off, float lvl,
    const float* __restrict__ wp, const float* __restrict__ conv_b,
    const float* __restrict__ cls_w, const float* __restrict__ cls_b,
    const float* __restrict__ bbox_w, const float* __restrict__ bbox_b,
    float* __restrict__ A_score, float* __restrict__ A_masked, float* __restrict__ A_boxoff,
    float* smem, float (*s_out)[16])
{
  constexpr int W    = H;
  constexpr int NBY  = H/2;
  constexpr int P    = 2*TX;            // outputs per block
  constexpr int ROWW = TX + 4;          // window x0-1 .. x0+TX+2
  constexpr int CIST = 4*ROWW;          // 4 input rows per ci in stage
  constexpr int CHFL = 32*CIST;         // floats per 32-ci chunk
  constexpr int NSTG = (CHFL + 255)/256;

  const int xb = lb % NBX;
  const int yb = (lb / NBX) % NBY;
  const int n  = lb / (NBX*NBY);
  const int x0 = xb * TX;
  const int y0 = yb * 2;
  const int co = threadIdx.x;
  const float* Fn = f + (size_t)n*256*H*W;
  float* lds_stage = smem;              // [2*CHBUF) during main loop
  float* lds_t     = smem;              // reused after main loop

  float acc[2][TX];
  #pragma unroll
  for (int o=0;o<2;o++)
    #pragma unroll
    for (int p=0;p<TX;p++) acc[o][p] = conv_b[co];

  // hoisted staging offsets: soff[k] is chunk-relative element offset, -1 = OOB zero
  int soff[NSTG];
  #pragma unroll
  for (int k=0;k<NSTG;k++){
    const int e  = co + k*256;
    const int cl = e / CIST;
    const int rem = e - cl*CIST;
    const int r  = rem / ROWW;
    const int j  = rem - r*ROWW;
    const int yg = y0 - 1 + r, xg = x0 - 1 + j;
    soff[k] = (e < CHFL && yg>=0 && yg<H && xg>=0 && xg<W)
            ? (cl*H + yg)*W + xg : -1;
  }

  // load + immediately store to LDS (short live ranges -> no spill)
#define STAGE(CB, BUF) do {                                                  \
    const float* Fb_ = Fn + (size_t)(CB)*H*W;                                \
    float st_[NSTG];                                                         \
    _Pragma("unroll")                                                        \
    for (int k=0;k<NSTG;k++)                                                 \
      st_[k] = (soff[k] >= 0) ? Fb_[soff[k]] : 0.f;                          \
    _Pragma("unroll")                                                        \
    for (int k=0;k<NSTG;k++){                                                \
      const int e = co + k*256;                                              \
      if (e < CHFL) (BUF)[e] = st_[k];                                       \
    }                                                                        \
  } while(0)

  // one ci: 4 input rows; row r -> acc[0](ky=r) and acc[1](ky=r-1)
#define CIFMA(SB, CL, WV) do {                                               \
    const float* bp_ = (SB) + (CL)*CIST;                                     \
    _Pragma("unroll")                                                        \
    for (int r=0;r<4;r++){                                                   \
      float rw_[ROWW];                                                       \
      _Pragma("unroll")                                                      \
      for (int q=0;q<ROWW/4;q++){                                            \
        float4 v_ = *(const float4*)(bp_ + r*ROWW + 4*q);                    \
        rw_[4*q+0]=v_.x; rw_[4*q+1]=v_.y;                                    \
        rw_[4*q+2]=v_.z; rw_[4*q+3]=v_.w;                                    \
      }                                                                      \
      if (r <= 2){                                                           \
        _Pragma("unroll")                                                    \
        for (int kx=0;kx<3;kx++){                                            \
          const float w_ = WV[r*3+kx];                                       \
          _Pragma("unroll")                                                  \
          for (int p=0;p<TX;p++) acc[0][p] = fmaf(w_, rw_[p+kx], acc[0][p]); \
        }                                                                    \
      }                                                                      \
      if (r >= 1){                                                           \
        _Pragma("unroll")                                                    \
        for (int kx=0;kx<3;kx++){                                            \
          const float w_ = WV[(r-1)*3+kx];                                   \
          _Pragma("unroll")                                                  \
          for (int p=0;p<TX;p++) acc[1][p] = fmaf(w_, rw_[p+kx], acc[1][p]); \
        }                                                                    \
      }                                                                      \
    }                                                                        \
  } while(0)

  STAGE(0, lds_stage);
  __syncthreads();

  for (int ch=0; ch<8; ++ch){
    const float* sb = lds_stage + (ch&1)*CHBUF;
    for (int cl=0; cl<32; ++cl){
      const int ci = ch*32 + cl;
      float wv[9];
      const float* wrow = wp + (size_t)ci*2304 + co;
      #pragma unroll
      for (int t=0;t<9;t++) wv[t] = wrow[t*256];
      CIFMA(sb, cl, wv);
    }
    if (ch<7){
      STAGE((ch+1)*32, lds_stage + ((ch+1)&1)*CHBUF);
      __syncthreads();
    }
  }
#undef STAGE
#undef CIFMA

  // guard: all waves done reading stage before lds_t overwrites it
  __syncthreads();

  // t tile -> LDS (stride 260: float4-aligned, 2-way-max banks)
  #pragma unroll
  for (int o=0;o<2;o++)
    #pragma unroll
    for (int p=0;p<TX;p++) lds_t[(o*TX+p)*260+co] = fmaxf(acc[o][p], 0.f);
  __syncthreads();

  {
    const int p = threadIdx.x % P;
    const int o = threadIdx.x / P;
    if (o < 15){
      const float* w1 = (o<3) ? (cls_w + o*256) : (bbox_w + (o-3)*256);
      float s = (o<3) ? cls_b[o] : bbox_b[o-3];
      const float4* wl = (const float4*)w1;
      const float4* tl = (const float4*)(lds_t + p*260);
      #pragma unroll 8
      for (int c=0;c<64;c++){
        float4 a = wl[c], b = tl[c];
        s += a.x*b.x + a.y*b.y + a.z*b.z + a.w*b.w;
      }
      s_out[o][p] = s;
    }
  }
  __syncthreads();

  if (threadIdx.x < 3*P){
    const int p = threadIdx.x / 3;
    const int a = threadIdx.x % 3;
    const int px = p % TX;
    const int yo = y0 + p / TX;
    float sraw = s_out[a][p];
    float dx = s_out[3+a*4+0][p];
    float dy = s_out[3+a*4+1][p];
    float dw = fminf(s_out[3+a*4+2][p], BBOX_CLIP);
    float dh = fminf(s_out[3+a*4+3][p], BBOX_CLIP);
    float ratio = (a==0)?0.5f:((a==1)?1.0f:2.0f);
    float hr = sqrtf(ratio);
    float wh2 = rintf(asize / hr * 0.5f);   // round-half-even == np.round (no .5 cases)
    float hh2 = rintf(asize * hr * 0.5f);
    float w = 2.f*wh2, h = 2.f*hh2;
    float cx = (float)((x0+px)*strd);
    float cy = (float)(yo*strd);
    float pcx = dx*w + cx, pcy = dy*h + cy;
    float pw = expf(dw)*w, ph = expf(dh)*h;
    float x1 = pcx - 0.5f*pw, y1 = pcy - 0.5f*ph;
    float x2 = pcx + 0.5f*pw, y2 = pcy + 0.5f*ph;
    x1 = fminf(fmaxf(x1,0.f),512.f); y1 = fminf(fmaxf(y1,0.f),512.f);
    x2 = fminf(fmaxf(x2,0.f),512.f); y2 = fminf(fmaxf(y2,0.f),512.f);
    bool valid = ((x2-x1) >= 1e-3f) && ((y2-y1) >= 1e-3f);
    float prob = 1.f/(1.f+expf(-sraw));
    float masked = valid ? prob : -1.f;
    float off = lvl*513.f;
    size_t gi = (size_t)n*FULL_PER_IMG + full_off + ((yo*W + (x0+px))*3 + a);
    A_score[gi]  = sraw;
    A_masked[gi] = masked;
    float4 bo; bo.x=x1+off; bo.y=y1+off; bo.z=x2+off; bo.w=y2+off;
    *(float4*)(A_boxoff + gi*4) = bo;
  }
}

// All 5 levels in ONE dispatch: 4096+1024+256+128+32 = 5536 blocks.
__global__ __launch_bounds__(256)
void conv_all(
    const float* __restrict__ f0, const float* __restrict__ f1,
    const float* __restrict__ f2, const float* __restrict__ f3,
    const float* __restrict__ f4,
    const float* __restrict__ wp, const float* __restrict__ conv_b,
    const float* __restrict__ cls_w, const float* __restrict__ cls_b,
    const float* __restrict__ bbox_w, const float* __restrict__ bbox_b,
    float* __restrict__ A_score, float* __restrict__ A_masked, float* __restrict__ A_boxoff)
{
  __shared__ float smem[SMEMF];
  __shared__ float s_out[15][16];
  const int b = blockIdx.x;
  if (b < 4096)
    conv_level< 8,128,16>(b,      f0,  4,  16.f,     0, 0.f, wp, conv_b, cls_w, cls_b, bbox_w, bbox_b, A_score, A_masked, A_boxoff, smem, s_out);
  else if (b < 5120)
    conv_level< 8, 64, 8>(b-4096, f1,  8,  32.f, 49152, 1.f, wp, conv_b, cls_w, cls_b, bbox_w, bbox_b, A_score, A_masked, A_boxoff, smem, s_out);
  else if (b < 5376)
    conv_level< 8, 32, 4>(b-5120, f2, 16,  64.f, 61440, 2.f, wp, conv_b, cls_w, cls_b, bbox_w, bbox_b, A_score, A_masked, A_boxoff, smem, s_out);
  else if (b < 5504)
    conv_level< 4, 16, 4>(b-5376, f3, 32, 128.f, 64512, 3.f, wp, conv_b, cls_w, cls_b, bbox_w, bbox_b, A_score, A_masked, A_boxoff, smem, s_out);
  else
    conv_level< 4,  8, 2>(b-5504, f4, 64, 256.f, 65280, 4.f, wp, conv_b, cls_w, cls_b, bbox_w, bbox_b, A_score, A_masked, A_boxoff, smem, s_out);
}

// blocks 0..11: exact top-1000 radix select per (img, lvl 0..2)
// blocks 12..15: lvl3+lvl4 passthrough copy (one block per image)
__global__ __launch_bounds__(1024) void select_kernel(
    const float* __restrict__ A_score, const float* __restrict__ A_masked,
    const float* __restrict__ A_boxoff,
    float* __restrict__ C_masked, float* __restrict__ C_boxoff)
{
  const int b = blockIdx.x;
  const int tid = threadIdx.x;
  if (b >= 12){
    const int n = b - 12;
    if (tid < 960){
      size_t gF = (size_t)n*FULL_PER_IMG + 64512 + tid;
      size_t gS = (size_t)n*SEL_PER_IMG  + 3000 + tid;
      C_masked[gS] = A_masked[gF];
      *(float4*)(C_boxoff + gS*4) = *(const float4*)(A_boxoff + gF*4);
    }
    return;
  }
  const int n = b / 3, lvl = b % 3;
  const int HWAs[3]  = {49152, 12288, 3072};
  const int FOFF[3]  = {0, 49152, 61440};
  const int HWA = HWAs[lvl];
  const size_t baseF = (size_t)n*FULL_PER_IMG + FOFF[lvl];
  const size_t baseS = (size_t)n*SEL_PER_IMG + lvl*1000;
  const int k = 1000;

  __shared__ unsigned int hist[256];
  __shared__ unsigned int sh_prefix, sh_krem, sh_c0, sh_c1, sh_above;
  if (tid==0){ sh_prefix=0u; sh_krem=(unsigned)k; }
  __syncthreads();

  for (int pass=3; pass>=0; pass--){
    if (tid < 256) hist[tid]=0u;
    __syncthreads();
    unsigned int pfx = sh_prefix;
    for (int i=tid;i<HWA;i+=1024){
      unsigned int u = sortkey(A_score[baseF+i]);
      if (pass==3 || (u >> ((pass+1)*8)) == pfx)
        atomicAdd(&hist[(u>>(pass*8)) & 255u], 1u);
    }
    __syncthreads();
    if (tid==0){
      unsigned int krem = sh_krem, accum = 0u; int chosen = 0;
      for (int bb=255; bb>=0; bb--){
        if (accum + hist[bb] >= krem){ chosen = bb; break; }
        accum += hist[bb];
      }
      sh_krem   = krem - accum;
      sh_prefix = (pfx<<8) | (unsigned)chosen;
    }
    __syncthreads();
  }
  const unsigned int T = sh_prefix;
  if (tid==0){ sh_c0=0u; sh_c1=0u; sh_above = (unsigned)k - sh_krem; }
  __syncthreads();
  const unsigned int nAbove = sh_above, need = sh_krem;

  for (int i=tid;i<HWA;i+=1024){
    unsigned int u = sortkey(A_score[baseF+i]);
    int pos = -1;
    if (u > T) pos = (int)atomicAdd(&sh_c0,1u);
    else if (u == T){
      unsigned int t = atomicAdd(&sh_c1,1u);
      if (t < need) pos = (int)(nAbove + t);
    }
    if (pos >= 0){
      C_masked[baseS+pos] = A_masked[baseF+i];
      *(float4*)(C_boxoff + (baseS+pos)*4) = *(const float4*)(A_boxoff + (baseF+i)*4);
    }
  }
}

// 256 threads, 16 consecutive candidates/thread, ONE barrier per pick:
// per-wave winner (v, idx, box) published in double-buffered LDS slots.
__global__ __launch_bounds__(256) void nms_kernel(
    const float* __restrict__ C_masked, const float* __restrict__ C_boxoff,
    float* __restrict__ out_b, float* __restrict__ out_s)
{
  const int n = blockIdx.x, tid = threadIdx.x;
  float  s[16];
  float4 b[16];
  #pragma unroll
  for (int j=0;j<16;j++){
    int i = tid*16 + j;
    if (i < SEL_PER_IMG){
      s[j] = C_masked[(size_t)n*SEL_PER_IMG + i];
      b[j] = *(const float4*)(C_boxoff + ((size_t)n*SEL_PER_IMG + i)*4);
    } else { s[j] = -2.f; b[j] = make_float4(0.f,0.f,0.f,0.f); }
  }
  __shared__ float wslot[2][4][6];   // [phase][wave][v, idx, x1,y1,x2,y2]

  for (int step=0; step<300; step++){
    float v = -3.f; int bi = 1<<30;
    #pragma unroll
    for (int j=0;j<16;j++){
      if (s[j] > v){ v = s[j]; bi = tid*16 + j; }    // strictly > : lowest idx on tie
    }
    #pragma unroll
    for (int m=32; m>=1; m>>=1){
      float ov = __shfl_xor(v, m); int oi = __shfl_xor(bi, m);
      if (ov > v || (ov == v && oi < bi)){ v = ov; bi = oi; }
    }
    // owning lane publishes its wave's winner (static-indexed scan, rule #20)
    float (*slot)[6] = wslot[step & 1];
    #pragma unroll
    for (int j=0;j<16;j++){
      if (tid*16 + j == bi){
        const int w = tid >> 6;
        slot[w][0] = v; slot[w][1] = __int_as_float(bi);
        slot[w][2] = b[j].x; slot[w][3] = b[j].y;
        slot[w][4] = b[j].z; slot[w][5] = b[j].w;
      }
    }
    __syncthreads();                                  // the only barrier
    float bv = slot[0][0]; int bidx = __float_as_int(slot[0][1]);
    float b0 = slot[0][2], b1 = slot[0][3], b2 = slot[0][4], b3 = slot[0][5];
    #pragma unroll
    for (int q=1;q<4;q++){
      float qv = slot[q][0]; int qi = __float_as_int(slot[q][1]);
      bool take = (qv > bv) || (qv == bv && qi < bidx);
      if (take){
        bv = qv; bidx = qi;
        b0 = slot[q][2]; b1 = slot[q][3]; b2 = slot[q][4]; b3 = slot[q][5];
      }
    }
    if (bv <= -0.5f) break;              // uniform; rest of d_out already zero
    float area_i = (b2-b0)*(b3-b1);
    #pragma unroll
    for (int j=0;j<16;j++){
      float xx1 = fmaxf(b0, b[j].x), yy1 = fmaxf(b1, b[j].y);
      float xx2 = fminf(b2, b[j].z), yy2 = fminf(b3, b[j].w);
      float iw = fmaxf(xx2-xx1, 0.f), ih = fmaxf(yy2-yy1, 0.f);
      float inter = iw*ih;
      float aj = (b[j].z-b[j].x)*(b[j].w-b[j].y);
      float iou = inter / fmaxf(area_i + aj - inter, 1e-9f);
      if (iou > 0.7f) s[j] = -1.f;
    }
    if (tid == 0){
      int lvl = (bidx<1000)?0:((bidx<2000)?1:((bidx<3000)?2:((bidx<3768)?3:4)));
      float off = (float)lvl * 513.f;
      size_t ob = ((size_t)n*300 + step)*4;
      out_b[ob+0]=b0-off; out_b[ob+1]=b1-off; out_b[ob+2]=b2-off; out_b[ob+3]=b3-off;
      out_s[(size_t)n*300 + step] = bv;
    }
  }
}

extern "C" void kernel_launch(void* const* d_in, const int* in_sizes, int n_in,
                              void* d_out, int out_size, void* d_ws, size_t ws_size,
                              hipStream_t stream) {
  (void)in_sizes; (void)n_in; (void)ws_size;
  const float* f0     = (const float*)d_in[1];
  const float* f1     = (const float*)d_in[2];
  const float* f2     = (const float*)d_in[3];
  const float* f3     = (const float*)d_in[4];
  const float* f4     = (const float*)d_in[5];
  const float* conv_w = (const float*)d_in[6];
  const float* conv_b = (const float*)d_in[7];
  const float* cls_w  = (const float*)d_in[8];
  const float* cls_b  = (const float*)d_in[9];
  const float* bbox_w = (const float*)d_in[10];
  const float* bbox_b = (const float*)d_in[11];

  float* ws       = (float*)d_ws;
  float* wp       = ws;                       // 589824
  float* A_score  = wp       + 589824;        // 261888
  float* A_masked = A_score  + 261888;        // 261888
  float* A_boxoff = A_masked + 261888;        // 1047552
  float* C_masked = A_boxoff + 1047552;       // 15840
  float* C_boxoff = C_masked + 15840;         // 63360

  float* out_b = (float*)d_out;               // [4][300][4]
  float* out_s = out_b + 4800;                // [4][300]

  hipMemsetAsync(d_out, 0, (size_t)out_size*sizeof(float), stream);

  repack_w<<<2304, 256, 0, stream>>>(conv_w, wp);

  conv_all<<<5536, 256, 0, stream>>>(f0, f1, f2, f3, f4,
      wp, conv_b, cls_w, cls_b, bbox_w, bbox_b, A_score, A_masked, A_boxoff);

  select_kernel<<<16, 1024, 0, stream>>>(A_score, A_masked, A_boxoff, C_masked, C_boxoff);
  nms_kernel<<<4, 256, 0, stream>>>(C_masked, C_boxoff, out_b, out_s);
}

// Round 12
// 1867.931 us; speedup vs baseline: 1.3103x; 1.1740x over previous
//
#include <hip/hip_runtime.h>

#define FULL_PER_IMG 65472
#define SEL_PER_IMG  3960
#define BBOX_CLIP    4.135166556742356f

__device__ __forceinline__ unsigned int sortkey(float f){
  unsigned int u = __float_as_uint(f);
  return (u & 0x80000000u) ? ~u : (u | 0x80000000u);
}

// conv_w [co][ci][3][3] -> wp [ci][tap][co]  (lane-coalesced by co)
__global__ __launch_bounds__(256) void repack_w(const float* __restrict__ src,
                                                float* __restrict__ dst){
  int idx = blockIdx.x*256 + threadIdx.x;     // 589824 total
  if (idx >= 589824) return;
  int co = idx & 255;
  int kt = idx >> 8;          // ci*9+tap
  int ci = kt / 9, tap = kt % 9;
  dst[idx] = src[co*2304 + ci*9 + tap];
}

#define CHBUF 1536   // floats per stage buffer (TX=8: 32*4*12)
#define SMEMF 4160   // union: max(2*CHBUF=3072, lds_t 16*260=4160) floats

// R8/R11 conv structure (VGPR 64, LDS 17.9KB, 1451us verified) — unchanged.
template<int TX, int H, int NBX>
__device__ void conv_level(int lb,
    const float* __restrict__ f, int strd, float asize, int full_off, float lvl,
    const float* __restrict__ wp, const float* __restrict__ conv_b,
    const float* __restrict__ cls_w, const float* __restrict__ cls_b,
    const float* __restrict__ bbox_w, const float* __restrict__ bbox_b,
    float* __restrict__ A_score, float* __restrict__ A_masked, float* __restrict__ A_boxoff,
    float* smem, float (*s_out)[16])
{
  constexpr int W    = H;
  constexpr int NBY  = H/2;
  constexpr int P    = 2*TX;            // outputs per block
  constexpr int ROWW = TX + 4;          // window x0-1 .. x0+TX+2
  constexpr int CIST = 4*ROWW;          // 4 input rows per ci in stage
  constexpr int CHFL = 32*CIST;         // floats per 32-ci chunk
  constexpr int NSTG = (CHFL + 255)/256;

  const int xb = lb % NBX;
  const int yb = (lb / NBX) % NBY;
  const int n  = lb / (NBX*NBY);
  const int x0 = xb * TX;
  const int y0 = yb * 2;
  const int co = threadIdx.x;
  const float* Fn = f + (size_t)n*256*H*W;
  float* lds_stage = smem;              // [2*CHBUF) during main loop
  float* lds_t     = smem;              // reused after main loop

  float acc[2][TX];
  #pragma unroll
  for (int o=0;o<2;o++)
    #pragma unroll
    for (int p=0;p<TX;p++) acc[o][p] = conv_b[co];

  // hoisted staging offsets: soff[k] is chunk-relative element offset, -1 = OOB zero
  int soff[NSTG];
  #pragma unroll
  for (int k=0;k<NSTG;k++){
    const int e  = co + k*256;
    const int cl = e / CIST;
    const int rem = e - cl*CIST;
    const int r  = rem / ROWW;
    const int j  = rem - r*ROWW;
    const int yg = y0 - 1 + r, xg = x0 - 1 + j;
    soff[k] = (e < CHFL && yg>=0 && yg<H && xg>=0 && xg<W)
            ? (cl*H + yg)*W + xg : -1;
  }

  // load + immediately store to LDS (short live ranges -> no spill)
#define STAGE(CB, BUF) do {                                                  \
    const float* Fb_ = Fn + (size_t)(CB)*H*W;                                \
    float st_[NSTG];                                                         \
    _Pragma("unroll")                                                        \
    for (int k=0;k<NSTG;k++)                                                 \
      st_[k] = (soff[k] >= 0) ? Fb_[soff[k]] : 0.f;                          \
    _Pragma("unroll")                                                        \
    for (int k=0;k<NSTG;k++){                                                \
      const int e = co + k*256;                                              \
      if (e < CHFL) (BUF)[e] = st_[k];                                       \
    }                                                                        \
  } while(0)

  // one ci: 4 input rows; row r -> acc[0](ky=r) and acc[1](ky=r-1)
#define CIFMA(SB, CL, WV) do {                                               \
    const float* bp_ = (SB) + (CL)*CIST;                                     \
    _Pragma("unroll")                                                        \
    for (int r=0;r<4;r++){                                                   \
      float rw_[ROWW];                                                       \
      _Pragma("unroll")                                                      \
      for (int q=0;q<ROWW/4;q++){                                            \
        float4 v_ = *(const float4*)(bp_ + r*ROWW + 4*q);                    \
        rw_[4*q+0]=v_.x; rw_[4*q+1]=v_.y;                                    \
        rw_[4*q+2]=v_.z; rw_[4*q+3]=v_.w;                                    \
      }                                                                      \
      if (r <= 2){                                                           \
        _Pragma("unroll")                                                    \
        for (int kx=0;kx<3;kx++){                                            \
          const float w_ = WV[r*3+kx];                                       \
          _Pragma("unroll")                                                  \
          for (int p=0;p<TX;p++) acc[0][p] = fmaf(w_, rw_[p+kx], acc[0][p]); \
        }                                                                    \
      }                                                                      \
      if (r >= 1){                                                           \
        _Pragma("unroll")                                                    \
        for (int kx=0;kx<3;kx++){                                            \
          const float w_ = WV[(r-1)*3+kx];                                   \
          _Pragma("unroll")                                                  \
          for (int p=0;p<TX;p++) acc[1][p] = fmaf(w_, rw_[p+kx], acc[1][p]); \
        }                                                                    \
      }                                                                      \
    }                                                                        \
  } while(0)

  STAGE(0, lds_stage);
  __syncthreads();

  for (int ch=0; ch<8; ++ch){
    const float* sb = lds_stage + (ch&1)*CHBUF;
    for (int cl=0; cl<32; ++cl){
      const int ci = ch*32 + cl;
      float wv[9];
      const float* wrow = wp + (size_t)ci*2304 + co;
      #pragma unroll
      for (int t=0;t<9;t++) wv[t] = wrow[t*256];
      CIFMA(sb, cl, wv);
    }
    if (ch<7){
      STAGE((ch+1)*32, lds_stage + ((ch+1)&1)*CHBUF);
      __syncthreads();
    }
  }
#undef STAGE
#undef CIFMA

  // guard: all waves done reading stage before lds_t overwrites it
  __syncthreads();

  // t tile -> LDS (stride 260: float4-aligned, 2-way-max banks)
  #pragma unroll
  for (int o=0;o<2;o++)
    #pragma unroll
    for (int p=0;p<TX;p++) lds_t[(o*TX+p)*260+co] = fmaxf(acc[o][p], 0.f);
  __syncthreads();

  {
    const int p = threadIdx.x % P;
    const int o = threadIdx.x / P;
    if (o < 15){
      const float* w1 = (o<3) ? (cls_w + o*256) : (bbox_w + (o-3)*256);
      float s = (o<3) ? cls_b[o] : bbox_b[o-3];
      const float4* wl = (const float4*)w1;
      const float4* tl = (const float4*)(lds_t + p*260);
      #pragma unroll 8
      for (int c=0;c<64;c++){
        float4 a = wl[c], b = tl[c];
        s += a.x*b.x + a.y*b.y + a.z*b.z + a.w*b.w;
      }
      s_out[o][p] = s;
    }
  }
  __syncthreads();

  if (threadIdx.x < 3*P){
    const int p = threadIdx.x / 3;
    const int a = threadIdx.x % 3;
    const int px = p % TX;
    const int yo = y0 + p / TX;
    float sraw = s_out[a][p];
    float dx = s_out[3+a*4+0][p];
    float dy = s_out[3+a*4+1][p];
    float dw = fminf(s_out[3+a*4+2][p], BBOX_CLIP);
    float dh = fminf(s_out[3+a*4+3][p], BBOX_CLIP);
    float ratio = (a==0)?0.5f:((a==1)?1.0f:2.0f);
    float hr = sqrtf(ratio);
    float wh2 = rintf(asize / hr * 0.5f);   // round-half-even == np.round (no .5 cases)
    float hh2 = rintf(asize * hr * 0.5f);
    float w = 2.f*wh2, h = 2.f*hh2;
    float cx = (float)((x0+px)*strd);
    float cy = (float)(yo*strd);
    float pcx = dx*w + cx, pcy = dy*h + cy;
    float pw = expf(dw)*w, ph = expf(dh)*h;
    float x1 = pcx - 0.5f*pw, y1 = pcy - 0.5f*ph;
    float x2 = pcx + 0.5f*pw, y2 = pcy + 0.5f*ph;
    x1 = fminf(fmaxf(x1,0.f),512.f); y1 = fminf(fmaxf(y1,0.f),512.f);
    x2 = fminf(fmaxf(x2,0.f),512.f); y2 = fminf(fmaxf(y2,0.f),512.f);
    bool valid = ((x2-x1) >= 1e-3f) && ((y2-y1) >= 1e-3f);
    float prob = 1.f/(1.f+expf(-sraw));
    float masked = valid ? prob : -1.f;
    float off = lvl*513.f;
    size_t gi = (size_t)n*FULL_PER_IMG + full_off + ((yo*W + (x0+px))*3 + a);
    A_score[gi]  = sraw;
    A_masked[gi] = masked;
    float4 bo; bo.x=x1+off; bo.y=y1+off; bo.z=x2+off; bo.w=y2+off;
    *(float4*)(A_boxoff + gi*4) = bo;
  }
}

// All 5 levels in ONE dispatch: 4096+1024+256+128+32 = 5536 blocks.
__global__ __launch_bounds__(256)
void conv_all(
    const float* __restrict__ f0, const float* __restrict__ f1,
    const float* __restrict__ f2, const float* __restrict__ f3,
    const float* __restrict__ f4,
    const float* __restrict__ wp, const float* __restrict__ conv_b,
    const float* __restrict__ cls_w, const float* __restrict__ cls_b,
    const float* __restrict__ bbox_w, const float* __restrict__ bbox_b,
    float* __restrict__ A_score, float* __restrict__ A_masked, float* __restrict__ A_boxoff)
{
  __shared__ float smem[SMEMF];
  __shared__ float s_out[15][16];
  const int b = blockIdx.x;
  if (b < 4096)
    conv_level< 8,128,16>(b,      f0,  4,  16.f,     0, 0.f, wp, conv_b, cls_w, cls_b, bbox_w, bbox_b, A_score, A_masked, A_boxoff, smem, s_out);
  else if (b < 5120)
    conv_level< 8, 64, 8>(b-4096, f1,  8,  32.f, 49152, 1.f, wp, conv_b, cls_w, cls_b, bbox_w, bbox_b, A_score, A_masked, A_boxoff, smem, s_out);
  else if (b < 5376)
    conv_level< 8, 32, 4>(b-5120, f2, 16,  64.f, 61440, 2.f, wp, conv_b, cls_w, cls_b, bbox_w, bbox_b, A_score, A_masked, A_boxoff, smem, s_out);
  else if (b < 5504)
    conv_level< 4, 16, 4>(b-5376, f3, 32, 128.f, 64512, 3.f, wp, conv_b, cls_w, cls_b, bbox_w, bbox_b, A_score, A_masked, A_boxoff, smem, s_out);
  else
    conv_level< 4,  8, 2>(b-5504, f4, 64, 256.f, 65280, 4.f, wp, conv_b, cls_w, cls_b, bbox_w, bbox_b, A_score, A_masked, A_boxoff, smem, s_out);
}

// blocks 0..11: exact top-1000 radix select per (img, lvl 0..2)
// blocks 12..15: lvl3+lvl4 passthrough copy (one block per image)
__global__ __launch_bounds__(1024) void select_kernel(
    const float* __restrict__ A_score, const float* __restrict__ A_masked,
    const float* __restrict__ A_boxoff,
    float* __restrict__ C_masked, float* __restrict__ C_boxoff)
{
  const int b = blockIdx.x;
  const int tid = threadIdx.x;
  if (b >= 12){
    const int n = b - 12;
    if (tid < 960){
      size_t gF = (size_t)n*FULL_PER_IMG + 64512 + tid;
      size_t gS = (size_t)n*SEL_PER_IMG  + 3000 + tid;
      C_masked[gS] = A_masked[gF];
      *(float4*)(C_boxoff + gS*4) = *(const float4*)(A_boxoff + gF*4);
    }
    return;
  }
  const int n = b / 3, lvl = b % 3;
  const int HWAs[3]  = {49152, 12288, 3072};
  const int FOFF[3]  = {0, 49152, 61440};
  const int HWA = HWAs[lvl];
  const size_t baseF = (size_t)n*FULL_PER_IMG + FOFF[lvl];
  const size_t baseS = (size_t)n*SEL_PER_IMG + lvl*1000;
  const int k = 1000;

  __shared__ unsigned int hist[256];
  __shared__ unsigned int sh_prefix, sh_krem, sh_c0, sh_c1, sh_above;
  if (tid==0){ sh_prefix=0u; sh_krem=(unsigned)k; }
  __syncthreads();

  for (int pass=3; pass>=0; pass--){
    if (tid < 256) hist[tid]=0u;
    __syncthreads();
    unsigned int pfx = sh_prefix;
    for (int i=tid;i<HWA;i+=1024){
      unsigned int u = sortkey(A_score[baseF+i]);
      if (pass==3 || (u >> ((pass+1)*8)) == pfx)
        atomicAdd(&hist[(u>>(pass*8)) & 255u], 1u);
    }
    __syncthreads();
    if (tid==0){
      unsigned int krem = sh_krem, accum = 0u; int chosen = 0;
      for (int bb=255; bb>=0; bb--){
        if (accum + hist[bb] >= krem){ chosen = bb; break; }
        accum += hist[bb];
      }
      sh_krem   = krem - accum;
      sh_prefix = (pfx<<8) | (unsigned)chosen;
    }
    __syncthreads();
  }
  const unsigned int T = sh_prefix;
  if (tid==0){ sh_c0=0u; sh_c1=0u; sh_above = (unsigned)k - sh_krem; }
  __syncthreads();
  const unsigned int nAbove = sh_above, need = sh_krem;

  for (int i=tid;i<HWA;i+=1024){
    unsigned int u = sortkey(A_score[baseF+i]);
    int pos = -1;
    if (u > T) pos = (int)atomicAdd(&sh_c0,1u);
    else if (u == T){
      unsigned int t = atomicAdd(&sh_c1,1u);
      if (t < need) pos = (int)(nAbove + t);
    }
    if (pos >= 0){
      C_masked[baseS+pos] = A_masked[baseF+i];
      *(float4*)(C_boxoff + (baseS+pos)*4) = *(const float4*)(A_boxoff + (baseF+i)*4);
    }
  }
}

// NMS as sort-then-scan (exactly equivalent to greedy argmax-NMS):
// 1) bitonic sort 4096 keys (score desc, idx asc) in LDS, 256 threads;
// 2) single-wave scan: accept iff IoU <= 0.7 vs all previously accepted.
__global__ __launch_bounds__(256) void nms_kernel(
    const float* __restrict__ C_masked, const float* __restrict__ C_boxoff,
    float* __restrict__ out_b, float* __restrict__ out_s)
{
  const int n = blockIdx.x, tid = threadIdx.x;
  __shared__ unsigned long long keys[4096];
  __shared__ float accb[304][4];

  // fill: key = sortkey(masked)<<32 | ~idx  (desc score, asc idx on tie)
  #pragma unroll
  for (int s=0; s<16; ++s){
    int i = s*256 + tid;
    unsigned long long kk = 0ull;
    if (i < SEL_PER_IMG){
      unsigned int sk = sortkey(C_masked[(size_t)n*SEL_PER_IMG + i]);
      kk = ((unsigned long long)sk << 32) | (unsigned int)(~(unsigned int)i);
    }
    keys[i] = kk;
  }
  __syncthreads();

  // bitonic sort, descending
  for (int k = 2; k <= 4096; k <<= 1){
    for (int j = k >> 1; j > 0; j >>= 1){
      #pragma unroll
      for (int s=0; s<16; ++s){
        int i = s*256 + tid;
        int ixj = i ^ j;
        if (ixj > i){
          unsigned long long a = keys[i], b = keys[ixj];
          bool up = ((i & k) == 0);
          bool sw = up ? (a < b) : (a > b);
          if (sw){ keys[i] = b; keys[ixj] = a; }
        }
      }
      __syncthreads();
    }
  }

  if (tid >= 64) return;        // single-wave scan, no more barriers
  const unsigned int THRK = sortkey(-0.5f);   // accept requires khi > this
  int nAcc = 0;
  for (int i = 0; i < 4096 && nAcc < 300; ++i){
    unsigned long long kk = keys[i];
    unsigned int khi = (unsigned int)(kk >> 32);
    if (khi <= THRK) break;                    // score <= -0.5: rest are too
    int idx = (int)(~(unsigned int)kk);
    float4 bx = *(const float4*)(C_boxoff + ((size_t)n*SEL_PER_IMG + idx)*4);
    // IoU vs accepted: lane t covers accepted t, t+64, ... (up to 300)
    bool sup = false;
    #pragma unroll
    for (int q=0; q<5; ++q){
      int a = tid + q*64;
      if (a < nAcc){
        float a0=accb[a][0], a1=accb[a][1], a2=accb[a][2], a3=accb[a][3];
        float xx1 = fmaxf(a0, bx.x), yy1 = fmaxf(a1, bx.y);
        float xx2 = fminf(a2, bx.z), yy2 = fminf(a3, bx.w);
        float iw = fmaxf(xx2-xx1, 0.f), ih = fmaxf(yy2-yy1, 0.f);
        float inter = iw*ih;
        float ar_a = (a2-a0)*(a3-a1);
        float ar_b = (bx.z-bx.x)*(bx.w-bx.y);
        float iou = inter / fmaxf(ar_a + ar_b - inter, 1e-9f);
        sup |= (iou > 0.7f);
      }
    }
    if (__ballot(sup) == 0ull){
      if (tid == 0){
        accb[nAcc][0]=bx.x; accb[nAcc][1]=bx.y; accb[nAcc][2]=bx.z; accb[nAcc][3]=bx.w;
        int lvl = (idx<1000)?0:((idx<2000)?1:((idx<3000)?2:((idx<3768)?3:4)));
        float off = (float)lvl * 513.f;
        size_t ob = ((size_t)n*300 + nAcc)*4;
        out_b[ob+0]=bx.x-off; out_b[ob+1]=bx.y-off; out_b[ob+2]=bx.z-off; out_b[ob+3]=bx.w-off;
        out_s[(size_t)n*300 + nAcc] = C_masked[(size_t)n*SEL_PER_IMG + idx];
      }
      ++nAcc;
    }
  }
}

extern "C" void kernel_launch(void* const* d_in, const int* in_sizes, int n_in,
                              void* d_out, int out_size, void* d_ws, size_t ws_size,
                              hipStream_t stream) {
  (void)in_sizes; (void)n_in; (void)ws_size;
  const float* f0     = (const float*)d_in[1];
  const float* f1     = (const float*)d_in[2];
  const float* f2     = (const float*)d_in[3];
  const float* f3     = (const float*)d_in[4];
  const float* f4     = (const float*)d_in[5];
  const float* conv_w = (const float*)d_in[6];
  const float* conv_b = (const float*)d_in[7];
  const float* cls_w  = (const float*)d_in[8];
  const float* cls_b  = (const float*)d_in[9];
  const float* bbox_w = (const float*)d_in[10];
  const float* bbox_b = (const float*)d_in[11];

  float* ws       = (float*)d_ws;
  float* wp       = ws;                       // 589824
  float* A_score  = wp       + 589824;        // 261888
  float* A_masked = A_score  + 261888;        // 261888
  float* A_boxoff = A_masked + 261888;        // 1047552
  float* C_masked = A_boxoff + 1047552;       // 15840
  float* C_boxoff = C_masked + 15840;         // 63360

  float* out_b = (float*)d_out;               // [4][300][4]
  float* out_s = out_b + 4800;                // [4][300]

  hipMemsetAsync(d_out, 0, (size_t)out_size*sizeof(float), stream);

  repack_w<<<2304, 256, 0, stream>>>(conv_w, wp);

  conv_all<<<5536, 256, 0, stream>>>(f0, f1, f2, f3, f4,
      wp, conv_b, cls_w, cls_b, bbox_w, bbox_b, A_score, A_masked, A_boxoff);

  select_kernel<<<16, 1024, 0, stream>>>(A_score, A_masked, A_boxoff, C_masked, C_boxoff);
  nms_kernel<<<4, 256, 0, stream>>>(C_masked, C_boxoff, out_b, out_s);
}

// Round 13
// 1866.692 us; speedup vs baseline: 1.3112x; 1.0007x over previous
//
#include <hip/hip_runtime.h>

#define FULL_PER_IMG 65472
#define SEL_PER_IMG  3960
#define BBOX_CLIP    4.135166556742356f

__device__ __forceinline__ unsigned int sortkey(float f){
  unsigned int u = __float_as_uint(f);
  return (u & 0x80000000u) ? ~u : (u | 0x80000000u);
}

// conv_w [co][ci][3][3] -> wp [ci][co][12]  (16B-aligned rows: 2x dwordx4 + dword)
__global__ __launch_bounds__(256) void repack_w(const float* __restrict__ src,
                                                float* __restrict__ dst){
  int idx = blockIdx.x*256 + threadIdx.x;     // 256*256*12 = 786432 total
  if (idx >= 786432) return;
  int t  = idx % 12;
  int rc = idx / 12;          // ci*256 + co
  int co = rc & 255;
  int ci = rc >> 8;
  dst[idx] = (t < 9) ? src[co*2304 + ci*9 + t] : 0.f;
}

#define CHBUF 1536   // floats per stage buffer (TX=8: 32*4*12)
#define SMEMF 4160   // union: max(2*CHBUF=3072, lds_t 16*260=4160) floats

// R8/R11 conv structure (VGPR 64, LDS 17.9KB, 1451us verified); weight
// fetch now 3 vector loads from [ci][co][12] layout (same 9 wv regs).
template<int TX, int H, int NBX>
__device__ void conv_level(int lb,
    const float* __restrict__ f, int strd, float asize, int full_off, float lvl,
    const float* __restrict__ wp, const float* __restrict__ conv_b,
    const float* __restrict__ cls_w, const float* __restrict__ cls_b,
    const float* __restrict__ bbox_w, const float* __restrict__ bbox_b,
    float* __restrict__ A_score, float* __restrict__ A_masked, float* __restrict__ A_boxoff,
    float* smem, float (*s_out)[16])
{
  constexpr int W    = H;
  constexpr int NBY  = H/2;
  constexpr int P    = 2*TX;            // outputs per block
  constexpr int ROWW = TX + 4;          // window x0-1 .. x0+TX+2
  constexpr int CIST = 4*ROWW;          // 4 input rows per ci in stage
  constexpr int CHFL = 32*CIST;         // floats per 32-ci chunk
  constexpr int NSTG = (CHFL + 255)/256;

  const int xb = lb % NBX;
  const int yb = (lb / NBX) % NBY;
  const int n  = lb / (NBX*NBY);
  const int x0 = xb * TX;
  const int y0 = yb * 2;
  const int co = threadIdx.x;
  const float* Fn = f + (size_t)n*256*H*W;
  float* lds_stage = smem;              // [2*CHBUF) during main loop
  float* lds_t     = smem;              // reused after main loop

  float acc[2][TX];
  #pragma unroll
  for (int o=0;o<2;o++)
    #pragma unroll
    for (int p=0;p<TX;p++) acc[o][p] = conv_b[co];

  // hoisted staging offsets: soff[k] is chunk-relative element offset, -1 = OOB zero
  int soff[NSTG];
  #pragma unroll
  for (int k=0;k<NSTG;k++){
    const int e  = co + k*256;
    const int cl = e / CIST;
    const int rem = e - cl*CIST;
    const int r  = rem / ROWW;
    const int j  = rem - r*ROWW;
    const int yg = y0 - 1 + r, xg = x0 - 1 + j;
    soff[k] = (e < CHFL && yg>=0 && yg<H && xg>=0 && xg<W)
            ? (cl*H + yg)*W + xg : -1;
  }

  // load + immediately store to LDS (short live ranges -> no spill)
#define STAGE(CB, BUF) do {                                                  \
    const float* Fb_ = Fn + (size_t)(CB)*H*W;                                \
    float st_[NSTG];                                                         \
    _Pragma("unroll")                                                        \
    for (int k=0;k<NSTG;k++)                                                 \
      st_[k] = (soff[k] >= 0) ? Fb_[soff[k]] : 0.f;                          \
    _Pragma("unroll")                                                        \
    for (int k=0;k<NSTG;k++){                                                \
      const int e = co + k*256;                                              \
      if (e < CHFL) (BUF)[e] = st_[k];                                       \
    }                                                                        \
  } while(0)

  // one ci: 4 input rows; row r -> acc[0](ky=r) and acc[1](ky=r-1)
#define CIFMA(SB, CL, WV) do {                                               \
    const float* bp_ = (SB) + (CL)*CIST;                                     \
    _Pragma("unroll")                                                        \
    for (int r=0;r<4;r++){                                                   \
      float rw_[ROWW];                                                       \
      _Pragma("unroll")                                                      \
      for (int q=0;q<ROWW/4;q++){                                            \
        float4 v_ = *(const float4*)(bp_ + r*ROWW + 4*q);                    \
        rw_[4*q+0]=v_.x; rw_[4*q+1]=v_.y;                                    \
        rw_[4*q+2]=v_.z; rw_[4*q+3]=v_.w;                                    \
      }                                                                      \
      if (r <= 2){                                                           \
        _Pragma("unroll")                                                    \
        for (int kx=0;kx<3;kx++){                                            \
          const float w_ = WV[r*3+kx];                                       \
          _Pragma("unroll")                                                  \
          for (int p=0;p<TX;p++) acc[0][p] = fmaf(w_, rw_[p+kx], acc[0][p]); \
        }                                                                    \
      }                                                                      \
      if (r >= 1){                                                           \
        _Pragma("unroll")                                                    \
        for (int kx=0;kx<3;kx++){                                            \
          const float w_ = WV[(r-1)*3+kx];                                   \
          _Pragma("unroll")                                                  \
          for (int p=0;p<TX;p++) acc[1][p] = fmaf(w_, rw_[p+kx], acc[1][p]); \
        }                                                                    \
      }                                                                      \
    }                                                                        \
  } while(0)

  STAGE(0, lds_stage);
  __syncthreads();

  for (int ch=0; ch<8; ++ch){
    const float* sb = lds_stage + (ch&1)*CHBUF;
    for (int cl=0; cl<32; ++cl){
      const int ci = ch*32 + cl;
      const float* wrow = wp + ((size_t)ci*256 + (size_t)co)*12;
      float4 wA = *(const float4*)(wrow);
      float4 wB = *(const float4*)(wrow + 4);
      float  w8 = wrow[8];
      float wv[9] = {wA.x,wA.y,wA.z,wA.w, wB.x,wB.y,wB.z,wB.w, w8};
      CIFMA(sb, cl, wv);
    }
    if (ch<7){
      STAGE((ch+1)*32, lds_stage + ((ch+1)&1)*CHBUF);
      __syncthreads();
    }
  }
#undef STAGE
#undef CIFMA

  // guard: all waves done reading stage before lds_t overwrites it
  __syncthreads();

  // t tile -> LDS (stride 260: float4-aligned, 2-way-max banks)
  #pragma unroll
  for (int o=0;o<2;o++)
    #pragma unroll
    for (int p=0;p<TX;p++) lds_t[(o*TX+p)*260+co] = fmaxf(acc[o][p], 0.f);
  __syncthreads();

  {
    const int p = threadIdx.x % P;
    const int o = threadIdx.x / P;
    if (o < 15){
      const float* w1 = (o<3) ? (cls_w + o*256) : (bbox_w + (o-3)*256);
      float s = (o<3) ? cls_b[o] : bbox_b[o-3];
      const float4* wl = (const float4*)w1;
      const float4* tl = (const float4*)(lds_t + p*260);
      #pragma unroll 8
      for (int c=0;c<64;c++){
        float4 a = wl[c], b = tl[c];
        s += a.x*b.x + a.y*b.y + a.z*b.z + a.w*b.w;
      }
      s_out[o][p] = s;
    }
  }
  __syncthreads();

  if (threadIdx.x < 3*P){
    const int p = threadIdx.x / 3;
    const int a = threadIdx.x % 3;
    const int px = p % TX;
    const int yo = y0 + p / TX;
    float sraw = s_out[a][p];
    float dx = s_out[3+a*4+0][p];
    float dy = s_out[3+a*4+1][p];
    float dw = fminf(s_out[3+a*4+2][p], BBOX_CLIP);
    float dh = fminf(s_out[3+a*4+3][p], BBOX_CLIP);
    float ratio = (a==0)?0.5f:((a==1)?1.0f:2.0f);
    float hr = sqrtf(ratio);
    float wh2 = rintf(asize / hr * 0.5f);   // round-half-even == np.round (no .5 cases)
    float hh2 = rintf(asize * hr * 0.5f);
    float w = 2.f*wh2, h = 2.f*hh2;
    float cx = (float)((x0+px)*strd);
    float cy = (float)(yo*strd);
    float pcx = dx*w + cx, pcy = dy*h + cy;
    float pw = expf(dw)*w, ph = expf(dh)*h;
    float x1 = pcx - 0.5f*pw, y1 = pcy - 0.5f*ph;
    float x2 = pcx + 0.5f*pw, y2 = pcy + 0.5f*ph;
    x1 = fminf(fmaxf(x1,0.f),512.f); y1 = fminf(fmaxf(y1,0.f),512.f);
    x2 = fminf(fmaxf(x2,0.f),512.f); y2 = fminf(fmaxf(y2,0.f),512.f);
    bool valid = ((x2-x1) >= 1e-3f) && ((y2-y1) >= 1e-3f);
    float prob = 1.f/(1.f+expf(-sraw));
    float masked = valid ? prob : -1.f;
    float off = lvl*513.f;
    size_t gi = (size_t)n*FULL_PER_IMG + full_off + ((yo*W + (x0+px))*3 + a);
    A_score[gi]  = sraw;
    A_masked[gi] = masked;
    float4 bo; bo.x=x1+off; bo.y=y1+off; bo.z=x2+off; bo.w=y2+off;
    *(float4*)(A_boxoff + gi*4) = bo;
  }
}

// All 5 levels in ONE dispatch: 4096+1024+256+128+32 = 5536 blocks.
__global__ __launch_bounds__(256)
void conv_all(
    const float* __restrict__ f0, const float* __restrict__ f1,
    const float* __restrict__ f2, const float* __restrict__ f3,
    const float* __restrict__ f4,
    const float* __restrict__ wp, const float* __restrict__ conv_b,
    const float* __restrict__ cls_w, const float* __restrict__ cls_b,
    const float* __restrict__ bbox_w, const float* __restrict__ bbox_b,
    float* __restrict__ A_score, float* __restrict__ A_masked, float* __restrict__ A_boxoff)
{
  __shared__ float smem[SMEMF];
  __shared__ float s_out[15][16];
  const int b = blockIdx.x;
  if (b < 4096)
    conv_level< 8,128,16>(b,      f0,  4,  16.f,     0, 0.f, wp, conv_b, cls_w, cls_b, bbox_w, bbox_b, A_score, A_masked, A_boxoff, smem, s_out);
  else if (b < 5120)
    conv_level< 8, 64, 8>(b-4096, f1,  8,  32.f, 49152, 1.f, wp, conv_b, cls_w, cls_b, bbox_w, bbox_b, A_score, A_masked, A_boxoff, smem, s_out);
  else if (b < 5376)
    conv_level< 8, 32, 4>(b-5120, f2, 16,  64.f, 61440, 2.f, wp, conv_b, cls_w, cls_b, bbox_w, bbox_b, A_score, A_masked, A_boxoff, smem, s_out);
  else if (b < 5504)
    conv_level< 4, 16, 4>(b-5376, f3, 32, 128.f, 64512, 3.f, wp, conv_b, cls_w, cls_b, bbox_w, bbox_b, A_score, A_masked, A_boxoff, smem, s_out);
  else
    conv_level< 4,  8, 2>(b-5504, f4, 64, 256.f, 65280, 4.f, wp, conv_b, cls_w, cls_b, bbox_w, bbox_b, A_score, A_masked, A_boxoff, smem, s_out);
}

// blocks 0..11: exact top-1000 radix select per (img, lvl 0..2)
//   per-wave sub-histograms: scores are CONCENTRATED (weights*0.01) -> a
//   single hist would serialize ~25k same-address LDS atomics per pass.
// blocks 12..15: lvl3+lvl4 passthrough copy (one block per image)
__global__ __launch_bounds__(1024) void select_kernel(
    const float* __restrict__ A_score, const float* __restrict__ A_masked,
    const float* __restrict__ A_boxoff,
    float* __restrict__ C_masked, float* __restrict__ C_boxoff)
{
  const int b = blockIdx.x;
  const int tid = threadIdx.x;
  if (b >= 12){
    const int n = b - 12;
    if (tid < 960){
      size_t gF = (size_t)n*FULL_PER_IMG + 64512 + tid;
      size_t gS = (size_t)n*SEL_PER_IMG  + 3000 + tid;
      C_masked[gS] = A_masked[gF];
      *(float4*)(C_boxoff + gS*4) = *(const float4*)(A_boxoff + gF*4);
    }
    return;
  }
  const int n = b / 3, lvl = b % 3;
  const int HWAs[3]  = {49152, 12288, 3072};
  const int FOFF[3]  = {0, 49152, 61440};
  const int HWA = HWAs[lvl];
  const size_t baseF = (size_t)n*FULL_PER_IMG + FOFF[lvl];
  const size_t baseS = (size_t)n*SEL_PER_IMG + lvl*1000;
  const int k = 1000;
  const int wid = tid >> 6;      // 16 waves

  __shared__ unsigned int hist[16][256];
  __shared__ unsigned int histM[256];
  __shared__ unsigned int sh_prefix, sh_krem, sh_c0, sh_c1, sh_above;
  if (tid==0){ sh_prefix=0u; sh_krem=(unsigned)k; }
  __syncthreads();

  for (int pass=3; pass>=0; pass--){
    unsigned int* hp = &hist[0][0];
    for (int z=tid; z<4096; z+=1024) hp[z] = 0u;
    __syncthreads();
    unsigned int pfx = sh_prefix;
    for (int i=tid;i<HWA;i+=1024){
      unsigned int u = sortkey(A_score[baseF+i]);
      if (pass==3 || (u >> ((pass+1)*8)) == pfx)
        atomicAdd(&hist[wid][(u>>(pass*8)) & 255u], 1u);
    }
    __syncthreads();
    if (tid < 256){
      unsigned int s = 0u;
      #pragma unroll
      for (int w=0;w<16;w++) s += hist[w][tid];
      histM[tid] = s;
    }
    __syncthreads();
    if (tid==0){
      unsigned int krem = sh_krem, accum = 0u; int chosen = 0;
      for (int bb=255; bb>=0; bb--){
        if (accum + histM[bb] >= krem){ chosen = bb; break; }
        accum += histM[bb];
      }
      sh_krem   = krem - accum;
      sh_prefix = (pfx<<8) | (unsigned)chosen;
    }
    __syncthreads();
  }
  const unsigned int T = sh_prefix;
  if (tid==0){ sh_c0=0u; sh_c1=0u; sh_above = (unsigned)k - sh_krem; }
  __syncthreads();
  const unsigned int nAbove = sh_above, need = sh_krem;

  for (int i=tid;i<HWA;i+=1024){
    unsigned int u = sortkey(A_score[baseF+i]);
    int pos = -1;
    if (u > T) pos = (int)atomicAdd(&sh_c0,1u);
    else if (u == T){
      unsigned int t = atomicAdd(&sh_c1,1u);
      if (t < need) pos = (int)(nAbove + t);
    }
    if (pos >= 0){
      C_masked[baseS+pos] = A_masked[baseF+i];
      *(float4*)(C_boxoff + (baseS+pos)*4) = *(const float4*)(A_boxoff + (baseF+i)*4);
    }
  }
}

// NMS sort-then-scan (== greedy argmax-NMS):
// 1) bitonic sort 4096 keys (score desc, idx asc);
// 2) top-1024 boxes cached in LDS; single-wave scan with next-iter prefetch.
__global__ __launch_bounds__(256) void nms_kernel(
    const float* __restrict__ C_masked, const float* __restrict__ C_boxoff,
    float* __restrict__ out_b, float* __restrict__ out_s)
{
  const int n = blockIdx.x, tid = threadIdx.x;
  __shared__ unsigned long long keys[4096];
  __shared__ float4 bcache[1024];
  __shared__ float accb[304][4];

  // fill: key = sortkey(masked)<<32 | ~idx  (desc score, asc idx on tie)
  #pragma unroll
  for (int s=0; s<16; ++s){
    int i = s*256 + tid;
    unsigned long long kk = 0ull;
    if (i < SEL_PER_IMG){
      unsigned int sk = sortkey(C_masked[(size_t)n*SEL_PER_IMG + i]);
      kk = ((unsigned long long)sk << 32) | (unsigned int)(~(unsigned int)i);
    }
    keys[i] = kk;
  }
  __syncthreads();

  // bitonic sort, descending
  for (int k = 2; k <= 4096; k <<= 1){
    for (int j = k >> 1; j > 0; j >>= 1){
      #pragma unroll
      for (int s=0; s<16; ++s){
        int i = s*256 + tid;
        int ixj = i ^ j;
        if (ixj > i){
          unsigned long long a = keys[i], b = keys[ixj];
          bool up = ((i & k) == 0);
          bool sw = up ? (a < b) : (a > b);
          if (sw){ keys[i] = b; keys[ixj] = a; }
        }
      }
      __syncthreads();
    }
  }

  // cache boxes for the top 1024 sorted slots (all are real candidates)
  for (int s=tid; s<1024; s+=256){
    int idx = (int)(~(unsigned int)keys[s]);
    bcache[s] = *(const float4*)(C_boxoff + ((size_t)n*SEL_PER_IMG + idx)*4);
  }
  __syncthreads();

  if (tid >= 64) return;        // single-wave scan, no more barriers
  const unsigned int THRK = sortkey(-0.5f);   // accept requires khi > this
  int nAcc = 0;
  unsigned long long kk = keys[0];
  float4 bx = bcache[0];
  for (int i = 0; i < 4096 && nAcc < 300; ++i){
    // prefetch next candidate (key + box) before this iteration's work
    unsigned long long kn = (i+1 < 4096) ? keys[i+1] : 0ull;
    unsigned int khin = (unsigned int)(kn >> 32);
    float4 bnext = make_float4(0.f,0.f,0.f,0.f);
    if (i+1 < 1024) bnext = bcache[i+1];
    else if (khin > THRK){
      int idn = (int)(~(unsigned int)kn);
      bnext = *(const float4*)(C_boxoff + ((size_t)n*SEL_PER_IMG + idn)*4);
    }
    unsigned int khi = (unsigned int)(kk >> 32);
    if (khi <= THRK) break;                    // score <= -0.5: rest are too
    bool sup = false;
    #pragma unroll
    for (int q=0; q<5; ++q){
      int a = tid + q*64;
      if (a < nAcc){
        float a0=accb[a][0], a1=accb[a][1], a2=accb[a][2], a3=accb[a][3];
        float xx1 = fmaxf(a0, bx.x), yy1 = fmaxf(a1, bx.y);
        float xx2 = fminf(a2, bx.z), yy2 = fminf(a3, bx.w);
        float iw = fmaxf(xx2-xx1, 0.f), ih = fmaxf(yy2-yy1, 0.f);
        float inter = iw*ih;
        float ar_a = (a2-a0)*(a3-a1);
        float ar_b = (bx.z-bx.x)*(bx.w-bx.y);
        float iou = inter / fmaxf(ar_a + ar_b - inter, 1e-9f);
        sup |= (iou > 0.7f);
      }
    }
    if (__ballot(sup) == 0ull){
      if (tid == 0){
        accb[nAcc][0]=bx.x; accb[nAcc][1]=bx.y; accb[nAcc][2]=bx.z; accb[nAcc][3]=bx.w;
        int idx = (int)(~(unsigned int)kk);
        int lvl = (idx<1000)?0:((idx<2000)?1:((idx<3000)?2:((idx<3768)?3:4)));
        float off = (float)lvl * 513.f;
        size_t ob = ((size_t)n*300 + nAcc)*4;
        out_b[ob+0]=bx.x-off; out_b[ob+1]=bx.y-off; out_b[ob+2]=bx.z-off; out_b[ob+3]=bx.w-off;
        out_s[(size_t)n*300 + nAcc] = __uint_as_float(khi & 0x7fffffffu); // prob >= 0: sortkey inverse
      }
      ++nAcc;
    }
    kk = kn; bx = bnext;
  }
}

extern "C" void kernel_launch(void* const* d_in, const int* in_sizes, int n_in,
                              void* d_out, int out_size, void* d_ws, size_t ws_size,
                              hipStream_t stream) {
  (void)in_sizes; (void)n_in; (void)ws_size;
  const float* f0     = (const float*)d_in[1];
  const float* f1     = (const float*)d_in[2];
  const float* f2     = (const float*)d_in[3];
  const float* f3     = (const float*)d_in[4];
  const float* f4     = (const float*)d_in[5];
  const float* conv_w = (const float*)d_in[6];
  const float* conv_b = (const float*)d_in[7];
  const float* cls_w  = (const float*)d_in[8];
  const float* cls_b  = (const float*)d_in[9];
  const float* bbox_w = (const float*)d_in[10];
  const float* bbox_b = (const float*)d_in[11];

  float* ws       = (float*)d_ws;
  float* wp       = ws;                       // 786432 ([ci][co][12])
  float* A_score  = wp       + 786432;        // 261888
  float* A_masked = A_score  + 261888;        // 261888
  float* A_boxoff = A_masked + 261888;        // 1047552
  float* C_masked = A_boxoff + 1047552;       // 15840
  float* C_boxoff = C_masked + 15840;         // 63360

  float* out_b = (float*)d_out;               // [4][300][4]
  float* out_s = out_b + 4800;                // [4][300]

  hipMemsetAsync(d_out, 0, (size_t)out_size*sizeof(float), stream);

  repack_w<<<3072, 256, 0, stream>>>(conv_w, wp);

  conv_all<<<5536, 256, 0, stream>>>(f0, f1, f2, f3, f4,
      wp, conv_b, cls_w, cls_b, bbox_w, bbox_b, A_score, A_masked, A_boxoff);

  select_kernel<<<16, 1024, 0, stream>>>(A_score, A_masked, A_boxoff, C_masked, C_boxoff);
  nms_kernel<<<4, 256, 0, stream>>>(C_masked, C_boxoff, out_b, out_s);
}

// Round 14
// 1825.925 us; speedup vs baseline: 1.3405x; 1.0223x over previous
//
#include <hip/hip_runtime.h>

#define FULL_PER_IMG 65472
#define SEL_PER_IMG  3960
#define BBOX_CLIP    4.135166556742356f

__device__ __forceinline__ unsigned int sortkey(float f){
  unsigned int u = __float_as_uint(f);
  return (u & 0x80000000u) ? ~u : (u | 0x80000000u);
}

// conv_w [co][ci][3][3] -> wp [ci][tap][co]  (lane-coalesced by co; R8 layout)
__global__ __launch_bounds__(256) void repack_w(const float* __restrict__ src,
                                                float* __restrict__ dst){
  int idx = blockIdx.x*256 + threadIdx.x;     // 589824 total
  if (idx >= 589824) return;
  int co = idx & 255;
  int kt = idx >> 8;          // ci*9+tap
  int ci = kt / 9, tap = kt % 9;
  dst[idx] = src[co*2304 + ci*9 + tap];
}

#define CHBUF 1536   // floats per stage buffer (TX=8: 32*4*12)
#define SMEMF 4160   // union: max(2*CHBUF=3072, lds_t 16*260=4160) floats

// R8/R11 conv structure; CIFMA now references float4 components DIRECTLY
// (compile-time-folded ternaries) — no intermediate rw_[] array, so no
// possibility of materialized v_mov unpacks. Same values, same FMA order
// (ci asc, ky asc, kx asc, p) -> bit-identical output.
template<int TX, int H, int NBX>
__device__ void conv_level(int lb,
    const float* __restrict__ f, int strd, float asize, int full_off, float lvl,
    const float* __restrict__ wp, const float* __restrict__ conv_b,
    const float* __restrict__ cls_w, const float* __restrict__ cls_b,
    const float* __restrict__ bbox_w, const float* __restrict__ bbox_b,
    float* __restrict__ A_score, float* __restrict__ A_masked, float* __restrict__ A_boxoff,
    float* smem, float (*s_out)[16])
{
  constexpr int W    = H;
  constexpr int NBY  = H/2;
  constexpr int P    = 2*TX;            // outputs per block
  constexpr int ROWW = TX + 4;          // window x0-1 .. x0+TX+2
  constexpr int CIST = 4*ROWW;          // 4 input rows per ci in stage
  constexpr int CHFL = 32*CIST;         // floats per 32-ci chunk
  constexpr int NSTG = (CHFL + 255)/256;

  const int xb = lb % NBX;
  const int yb = (lb / NBX) % NBY;
  const int n  = lb / (NBX*NBY);
  const int x0 = xb * TX;
  const int y0 = yb * 2;
  const int co = threadIdx.x;
  const float* Fn = f + (size_t)n*256*H*W;
  float* lds_stage = smem;              // [2*CHBUF) during main loop
  float* lds_t     = smem;              // reused after main loop

  float acc[2][TX];
  #pragma unroll
  for (int o=0;o<2;o++)
    #pragma unroll
    for (int p=0;p<TX;p++) acc[o][p] = conv_b[co];

  // hoisted staging offsets: soff[k] is chunk-relative element offset, -1 = OOB zero
  int soff[NSTG];
  #pragma unroll
  for (int k=0;k<NSTG;k++){
    const int e  = co + k*256;
    const int cl = e / CIST;
    const int rem = e - cl*CIST;
    const int r  = rem / ROWW;
    const int j  = rem - r*ROWW;
    const int yg = y0 - 1 + r, xg = x0 - 1 + j;
    soff[k] = (e < CHFL && yg>=0 && yg<H && xg>=0 && xg<W)
            ? (cl*H + yg)*W + xg : -1;
  }

  // load + immediately store to LDS (short live ranges -> no spill)
#define STAGE(CB, BUF) do {                                                  \
    const float* Fb_ = Fn + (size_t)(CB)*H*W;                                \
    float st_[NSTG];                                                         \
    _Pragma("unroll")                                                        \
    for (int k=0;k<NSTG;k++)                                                 \
      st_[k] = (soff[k] >= 0) ? Fb_[soff[k]] : 0.f;                          \
    _Pragma("unroll")                                                        \
    for (int k=0;k<NSTG;k++){                                                \
      const int e = co + k*256;                                              \
      if (e < CHFL) (BUF)[e] = st_[k];                                       \
    }                                                                        \
  } while(0)

  // compile-time component select (folds to a direct register reference)
#define CMP4_(Q,I) ((I)==0?(Q).x:((I)==1?(Q).y:((I)==2?(Q).z:(Q).w)))
#define EL_(I) ((I)<4 ? CMP4_(q0_,(I)) : ((I)<8 ? CMP4_(q1_,(I)-4) : CMP4_(q2_,(I)-8)))

  // one ci: 4 input rows; row r -> acc[0](ky=r) and acc[1](ky=r-1)
#define CIFMA(SB, CL, WV) do {                                               \
    const float* bp_ = (SB) + (CL)*CIST;                                     \
    _Pragma("unroll")                                                        \
    for (int r=0;r<4;r++){                                                   \
      float4 q0_ = *(const float4*)(bp_ + r*ROWW);                           \
      float4 q1_ = *(const float4*)(bp_ + r*ROWW + 4);                       \
      float4 q2_ = (ROWW > 8) ? *(const float4*)(bp_ + r*ROWW + 8)           \
                              : make_float4(0.f,0.f,0.f,0.f);                \
      if (r <= 2){                                                           \
        _Pragma("unroll")                                                    \
        for (int kx=0;kx<3;kx++){                                            \
          const float w_ = WV[r*3+kx];                                       \
          _Pragma("unroll")                                                  \
          for (int p=0;p<TX;p++) acc[0][p] = fmaf(w_, EL_(p+kx), acc[0][p]); \
        }                                                                    \
      }                                                                      \
      if (r >= 1){                                                           \
        _Pragma("unroll")                                                    \
        for (int kx=0;kx<3;kx++){                                            \
          const float w_ = WV[(r-1)*3+kx];                                   \
          _Pragma("unroll")                                                  \
          for (int p=0;p<TX;p++) acc[1][p] = fmaf(w_, EL_(p+kx), acc[1][p]); \
        }                                                                    \
      }                                                                      \
    }                                                                        \
  } while(0)

  STAGE(0, lds_stage);
  __syncthreads();

  for (int ch=0; ch<8; ++ch){
    const float* sb = lds_stage + (ch&1)*CHBUF;
    for (int cl=0; cl<32; ++cl){
      const int ci = ch*32 + cl;
      float wv[9];
      const float* wrow = wp + (size_t)ci*2304 + co;
      #pragma unroll
      for (int t=0;t<9;t++) wv[t] = wrow[t*256];
      CIFMA(sb, cl, wv);
    }
    if (ch<7){
      STAGE((ch+1)*32, lds_stage + ((ch+1)&1)*CHBUF);
      __syncthreads();
    }
  }
#undef STAGE
#undef CIFMA
#undef EL_
#undef CMP4_

  // guard: all waves done reading stage before lds_t overwrites it
  __syncthreads();

  // t tile -> LDS (stride 260: float4-aligned, 2-way-max banks)
  #pragma unroll
  for (int o=0;o<2;o++)
    #pragma unroll
    for (int p=0;p<TX;p++) lds_t[(o*TX+p)*260+co] = fmaxf(acc[o][p], 0.f);
  __syncthreads();

  {
    const int p = threadIdx.x % P;
    const int o = threadIdx.x / P;
    if (o < 15){
      const float* w1 = (o<3) ? (cls_w + o*256) : (bbox_w + (o-3)*256);
      float s = (o<3) ? cls_b[o] : bbox_b[o-3];
      const float4* wl = (const float4*)w1;
      const float4* tl = (const float4*)(lds_t + p*260);
      #pragma unroll 8
      for (int c=0;c<64;c++){
        float4 a = wl[c], b = tl[c];
        s += a.x*b.x + a.y*b.y + a.z*b.z + a.w*b.w;
      }
      s_out[o][p] = s;
    }
  }
  __syncthreads();

  if (threadIdx.x < 3*P){
    const int p = threadIdx.x / 3;
    const int a = threadIdx.x % 3;
    const int px = p % TX;
    const int yo = y0 + p / TX;
    float sraw = s_out[a][p];
    float dx = s_out[3+a*4+0][p];
    float dy = s_out[3+a*4+1][p];
    float dw = fminf(s_out[3+a*4+2][p], BBOX_CLIP);
    float dh = fminf(s_out[3+a*4+3][p], BBOX_CLIP);
    float ratio = (a==0)?0.5f:((a==1)?1.0f:2.0f);
    float hr = sqrtf(ratio);
    float wh2 = rintf(asize / hr * 0.5f);   // round-half-even == np.round (no .5 cases)
    float hh2 = rintf(asize * hr * 0.5f);
    float w = 2.f*wh2, h = 2.f*hh2;
    float cx = (float)((x0+px)*strd);
    float cy = (float)(yo*strd);
    float pcx = dx*w + cx, pcy = dy*h + cy;
    float pw = expf(dw)*w, ph = expf(dh)*h;
    float x1 = pcx - 0.5f*pw, y1 = pcy - 0.5f*ph;
    float x2 = pcx + 0.5f*pw, y2 = pcy + 0.5f*ph;
    x1 = fminf(fmaxf(x1,0.f),512.f); y1 = fminf(fmaxf(y1,0.f),512.f);
    x2 = fminf(fmaxf(x2,0.f),512.f); y2 = fminf(fmaxf(y2,0.f),512.f);
    bool valid = ((x2-x1) >= 1e-3f) && ((y2-y1) >= 1e-3f);
    float prob = 1.f/(1.f+expf(-sraw));
    float masked = valid ? prob : -1.f;
    float off = lvl*513.f;
    size_t gi = (size_t)n*FULL_PER_IMG + full_off + ((yo*W + (x0+px))*3 + a);
    A_score[gi]  = sraw;
    A_masked[gi] = masked;
    float4 bo; bo.x=x1+off; bo.y=y1+off; bo.z=x2+off; bo.w=y2+off;
    *(float4*)(A_boxoff + gi*4) = bo;
  }
}

// All 5 levels in ONE dispatch: 4096+1024+256+128+32 = 5536 blocks.
__global__ __launch_bounds__(256)
void conv_all(
    const float* __restrict__ f0, const float* __restrict__ f1,
    const float* __restrict__ f2, const float* __restrict__ f3,
    const float* __restrict__ f4,
    const float* __restrict__ wp, const float* __restrict__ conv_b,
    const float* __restrict__ cls_w, const float* __restrict__ cls_b,
    const float* __restrict__ bbox_w, const float* __restrict__ bbox_b,
    float* __restrict__ A_score, float* __restrict__ A_masked, float* __restrict__ A_boxoff)
{
  __shared__ float smem[SMEMF];
  __shared__ float s_out[15][16];
  const int b = blockIdx.x;
  if (b < 4096)
    conv_level< 8,128,16>(b,      f0,  4,  16.f,     0, 0.f, wp, conv_b, cls_w, cls_b, bbox_w, bbox_b, A_score, A_masked, A_boxoff, smem, s_out);
  else if (b < 5120)
    conv_level< 8, 64, 8>(b-4096, f1,  8,  32.f, 49152, 1.f, wp, conv_b, cls_w, cls_b, bbox_w, bbox_b, A_score, A_masked, A_boxoff, smem, s_out);
  else if (b < 5376)
    conv_level< 8, 32, 4>(b-5120, f2, 16,  64.f, 61440, 2.f, wp, conv_b, cls_w, cls_b, bbox_w, bbox_b, A_score, A_masked, A_boxoff, smem, s_out);
  else if (b < 5504)
    conv_level< 4, 16, 4>(b-5376, f3, 32, 128.f, 64512, 3.f, wp, conv_b, cls_w, cls_b, bbox_w, bbox_b, A_score, A_masked, A_boxoff, smem, s_out);
  else
    conv_level< 4,  8, 2>(b-5504, f4, 64, 256.f, 65280, 4.f, wp, conv_b, cls_w, cls_b, bbox_w, bbox_b, A_score, A_masked, A_boxoff, smem, s_out);
}

// blocks 0..11: exact top-1000 radix select per (img, lvl 0..2)
//   per-wave sub-histograms (concentrated scores -> same-address atomics)
// blocks 12..15: lvl3+lvl4 passthrough copy (one block per image)
__global__ __launch_bounds__(1024) void select_kernel(
    const float* __restrict__ A_score, const float* __restrict__ A_masked,
    const float* __restrict__ A_boxoff,
    float* __restrict__ C_masked, float* __restrict__ C_boxoff)
{
  const int b = blockIdx.x;
  const int tid = threadIdx.x;
  if (b >= 12){
    const int n = b - 12;
    if (tid < 960){
      size_t gF = (size_t)n*FULL_PER_IMG + 64512 + tid;
      size_t gS = (size_t)n*SEL_PER_IMG  + 3000 + tid;
      C_masked[gS] = A_masked[gF];
      *(float4*)(C_boxoff + gS*4) = *(const float4*)(A_boxoff + gF*4);
    }
    return;
  }
  const int n = b / 3, lvl = b % 3;
  const int HWAs[3]  = {49152, 12288, 3072};
  const int FOFF[3]  = {0, 49152, 61440};
  const int HWA = HWAs[lvl];
  const size_t baseF = (size_t)n*FULL_PER_IMG + FOFF[lvl];
  const size_t baseS = (size_t)n*SEL_PER_IMG + lvl*1000;
  const int k = 1000;
  const int wid = tid >> 6;      // 16 waves

  __shared__ unsigned int hist[16][256];
  __shared__ unsigned int histM[256];
  __shared__ unsigned int sh_prefix, sh_krem, sh_c0, sh_c1, sh_above;
  if (tid==0){ sh_prefix=0u; sh_krem=(unsigned)k; }
  __syncthreads();

  for (int pass=3; pass>=0; pass--){
    unsigned int* hp = &hist[0][0];
    for (int z=tid; z<4096; z+=1024) hp[z] = 0u;
    __syncthreads();
    unsigned int pfx = sh_prefix;
    for (int i=tid;i<HWA;i+=1024){
      unsigned int u = sortkey(A_score[baseF+i]);
      if (pass==3 || (u >> ((pass+1)*8)) == pfx)
        atomicAdd(&hist[wid][(u>>(pass*8)) & 255u], 1u);
    }
    __syncthreads();
    if (tid < 256){
      unsigned int s = 0u;
      #pragma unroll
      for (int w=0;w<16;w++) s += hist[w][tid];
      histM[tid] = s;
    }
    __syncthreads();
    if (tid==0){
      unsigned int krem = sh_krem, accum = 0u; int chosen = 0;
      for (int bb=255; bb>=0; bb--){
        if (accum + histM[bb] >= krem){ chosen = bb; break; }
        accum += histM[bb];
      }
      sh_krem   = krem - accum;
      sh_prefix = (pfx<<8) | (unsigned)chosen;
    }
    __syncthreads();
  }
  const unsigned int T = sh_prefix;
  if (tid==0){ sh_c0=0u; sh_c1=0u; sh_above = (unsigned)k - sh_krem; }
  __syncthreads();
  const unsigned int nAbove = sh_above, need = sh_krem;

  for (int i=tid;i<HWA;i+=1024){
    unsigned int u = sortkey(A_score[baseF+i]);
    int pos = -1;
    if (u > T) pos = (int)atomicAdd(&sh_c0,1u);
    else if (u == T){
      unsigned int t = atomicAdd(&sh_c1,1u);
      if (t < need) pos = (int)(nAbove + t);
    }
    if (pos >= 0){
      C_masked[baseS+pos] = A_masked[baseF+i];
      *(float4*)(C_boxoff + (baseS+pos)*4) = *(const float4*)(A_boxoff + (baseF+i)*4);
    }
  }
}

// NMS sort-then-scan (== greedy argmax-NMS):
// 1) bitonic sort 4096 keys (score desc, idx asc);
// 2) top-1024 boxes cached in LDS; single-wave scan with next-iter prefetch.
__global__ __launch_bounds__(256) void nms_kernel(
    const float* __restrict__ C_masked, const float* __restrict__ C_boxoff,
    float* __restrict__ out_b, float* __restrict__ out_s)
{
  const int n = blockIdx.x, tid = threadIdx.x;
  __shared__ unsigned long long keys[4096];
  __shared__ float4 bcache[1024];
  __shared__ float accb[304][4];

  // fill: key = sortkey(masked)<<32 | ~idx  (desc score, asc idx on tie)
  #pragma unroll
  for (int s=0; s<16; ++s){
    int i = s*256 + tid;
    unsigned long long kk = 0ull;
    if (i < SEL_PER_IMG){
      unsigned int sk = sortkey(C_masked[(size_t)n*SEL_PER_IMG + i]);
      kk = ((unsigned long long)sk << 32) | (unsigned int)(~(unsigned int)i);
    }
    keys[i] = kk;
  }
  __syncthreads();

  // bitonic sort, descending
  for (int k = 2; k <= 4096; k <<= 1){
    for (int j = k >> 1; j > 0; j >>= 1){
      #pragma unroll
      for (int s=0; s<16; ++s){
        int i = s*256 + tid;
        int ixj = i ^ j;
        if (ixj > i){
          unsigned long long a = keys[i], b = keys[ixj];
          bool up = ((i & k) == 0);
          bool sw = up ? (a < b) : (a > b);
          if (sw){ keys[i] = b; keys[ixj] = a; }
        }
      }
      __syncthreads();
    }
  }

  // cache boxes for the top 1024 sorted slots (all are real candidates)
  for (int s=tid; s<1024; s+=256){
    int idx = (int)(~(unsigned int)keys[s]);
    bcache[s] = *(const float4*)(C_boxoff + ((size_t)n*SEL_PER_IMG + idx)*4);
  }
  __syncthreads();

  if (tid >= 64) return;        // single-wave scan, no more barriers
  const unsigned int THRK = sortkey(-0.5f);   // accept requires khi > this
  int nAcc = 0;
  unsigned long long kk = keys[0];
  float4 bx = bcache[0];
  for (int i = 0; i < 4096 && nAcc < 300; ++i){
    // prefetch next candidate (key + box) before this iteration's work
    unsigned long long kn = (i+1 < 4096) ? keys[i+1] : 0ull;
    unsigned int khin = (unsigned int)(kn >> 32);
    float4 bnext = make_float4(0.f,0.f,0.f,0.f);
    if (i+1 < 1024) bnext = bcache[i+1];
    else if (khin > THRK){
      int idn = (int)(~(unsigned int)kn);
      bnext = *(const float4*)(C_boxoff + ((size_t)n*SEL_PER_IMG + idn)*4);
    }
    unsigned int khi = (unsigned int)(kk >> 32);
    if (khi <= THRK) break;                    // score <= -0.5: rest are too
    bool sup = false;
    #pragma unroll
    for (int q=0; q<5; ++q){
      int a = tid + q*64;
      if (a < nAcc){
        float a0=accb[a][0], a1=accb[a][1], a2=accb[a][2], a3=accb[a][3];
        float xx1 = fmaxf(a0, bx.x), yy1 = fmaxf(a1, bx.y);
        float xx2 = fminf(a2, bx.z), yy2 = fminf(a3, bx.w);
        float iw = fmaxf(xx2-xx1, 0.f), ih = fmaxf(yy2-yy1, 0.f);
        float inter = iw*ih;
        float ar_a = (a2-a0)*(a3-a1);
        float ar_b = (bx.z-bx.x)*(bx.w-bx.y);
        float iou = inter / fmaxf(ar_a + ar_b - inter, 1e-9f);
        sup |= (iou > 0.7f);
      }
    }
    if (__ballot(sup) == 0ull){
      if (tid == 0){
        accb[nAcc][0]=bx.x; accb[nAcc][1]=bx.y; accb[nAcc][2]=bx.z; accb[nAcc][3]=bx.w;
        int idx = (int)(~(unsigned int)kk);
        int lvl = (idx<1000)?0:((idx<2000)?1:((idx<3000)?2:((idx<3768)?3:4)));
        float off = (float)lvl * 513.f;
        size_t ob = ((size_t)n*300 + nAcc)*4;
        out_b[ob+0]=bx.x-off; out_b[ob+1]=bx.y-off; out_b[ob+2]=bx.z-off; out_b[ob+3]=bx.w-off;
        out_s[(size_t)n*300 + nAcc] = __uint_as_float(khi & 0x7fffffffu); // prob >= 0: sortkey inverse
      }
      ++nAcc;
    }
    kk = kn; bx = bnext;
  }
}

extern "C" void kernel_launch(void* const* d_in, const int* in_sizes, int n_in,
                              void* d_out, int out_size, void* d_ws, size_t ws_size,
                              hipStream_t stream) {
  (void)in_sizes; (void)n_in; (void)ws_size;
  const float* f0     = (const float*)d_in[1];
  const float* f1     = (const float*)d_in[2];
  const float* f2     = (const float*)d_in[3];
  const float* f3     = (const float*)d_in[4];
  const float* f4     = (const float*)d_in[5];
  const float* conv_w = (const float*)d_in[6];
  const float* conv_b = (const float*)d_in[7];
  const float* cls_w  = (const float*)d_in[8];
  const float* cls_b  = (const float*)d_in[9];
  const float* bbox_w = (const float*)d_in[10];
  const float* bbox_b = (const float*)d_in[11];

  float* ws       = (float*)d_ws;
  float* wp       = ws;                       // 589824 ([ci][tap][co])
  float* A_score  = wp       + 589824;        // 261888
  float* A_masked = A_score  + 261888;        // 261888
  float* A_boxoff = A_masked + 261888;        // 1047552
  float* C_masked = A_boxoff + 1047552;       // 15840
  float* C_boxoff = C_masked + 15840;         // 63360

  float* out_b = (float*)d_out;               // [4][300][4]
  float* out_s = out_b + 4800;                // [4][300]

  hipMemsetAsync(d_out, 0, (size_t)out_size*sizeof(float), stream);

  repack_w<<<2304, 256, 0, stream>>>(conv_w, wp);

  conv_all<<<5536, 256, 0, stream>>>(f0, f1, f2, f3, f4,
      wp, conv_b, cls_w, cls_b, bbox_w, bbox_b, A_score, A_masked, A_boxoff);

  select_kernel<<<16, 1024, 0, stream>>>(A_score, A_masked, A_boxoff, C_masked, C_boxoff);
  nms_kernel<<<4, 256, 0, stream>>>(C_masked, C_boxoff, out_b, out_s);
}

// Round 15
// 1797.660 us; speedup vs baseline: 1.3616x; 1.0157x over previous
//
#include <hip/hip_runtime.h>

#define FULL_PER_IMG 65472
#define SEL_PER_IMG  3960
#define BBOX_CLIP    4.135166556742356f

__device__ __forceinline__ unsigned int sortkey(float f){
  unsigned int u = __float_as_uint(f);
  return (u & 0x80000000u) ? ~u : (u | 0x80000000u);
}

// conv_w [co][ci][3][3] -> wp [ci][tap][co]  (same layout as before) via
// LDS-tiled transpose: 64co x 36kt tiles; 9-contiguous reads, coalesced writes.
__global__ __launch_bounds__(256) void repack_w(const float* __restrict__ src,
                                                float* __restrict__ dst){
  __shared__ float tile[64][37];
  const int b   = blockIdx.x;          // 256 blocks: 4 co-tiles x 64 kt-tiles
  const int co0 = (b & 3) * 64;
  const int kt0 = (b >> 2) * 36;
  const int t   = threadIdx.x;
  {
    const int co   = co0 + (t >> 2);
    const int part = t & 3;
    const float* s = src + (size_t)co*2304 + kt0 + part*9;
    #pragma unroll
    for (int j=0;j<9;j++) tile[co - co0][part*9 + j] = s[j];
  }
  __syncthreads();
  {
    const int c = t & 63;
    #pragma unroll
    for (int jj=0;jj<9;jj++){
      const int ktL = (t >> 6)*9 + jj;
      dst[(size_t)(kt0 + ktL)*256 + co0 + c] = tile[c][ktL];
    }
  }
}

#define CHBUF 1536   // floats per stage buffer (TX=8: 32*4*12)
#define SMEMF 4160   // union: max(2*CHBUF=3072, lds_t 16*260=4160) floats

// R8/R11/R14 conv structure — FROZEN at its measured floor (~1452us,
// VGPR 64, 86% VALUBusy; 4 structural variants all converge here).
template<int TX, int H, int NBX>
__device__ void conv_level(int lb,
    const float* __restrict__ f, int strd, float asize, int full_off, float lvl,
    const float* __restrict__ wp, const float* __restrict__ conv_b,
    const float* __restrict__ cls_w, const float* __restrict__ cls_b,
    const float* __restrict__ bbox_w, const float* __restrict__ bbox_b,
    float* __restrict__ A_score, float* __restrict__ A_masked, float* __restrict__ A_boxoff,
    float* smem, float (*s_out)[16])
{
  constexpr int W    = H;
  constexpr int NBY  = H/2;
  constexpr int P    = 2*TX;            // outputs per block
  constexpr int ROWW = TX + 4;          // window x0-1 .. x0+TX+2
  constexpr int CIST = 4*ROWW;          // 4 input rows per ci in stage
  constexpr int CHFL = 32*CIST;         // floats per 32-ci chunk
  constexpr int NSTG = (CHFL + 255)/256;

  const int xb = lb % NBX;
  const int yb = (lb / NBX) % NBY;
  const int n  = lb / (NBX*NBY);
  const int x0 = xb * TX;
  const int y0 = yb * 2;
  const int co = threadIdx.x;
  const float* Fn = f + (size_t)n*256*H*W;
  float* lds_stage = smem;              // [2*CHBUF) during main loop
  float* lds_t     = smem;              // reused after main loop

  float acc[2][TX];
  #pragma unroll
  for (int o=0;o<2;o++)
    #pragma unroll
    for (int p=0;p<TX;p++) acc[o][p] = conv_b[co];

  // hoisted staging offsets: soff[k] is chunk-relative element offset, -1 = OOB zero
  int soff[NSTG];
  #pragma unroll
  for (int k=0;k<NSTG;k++){
    const int e  = co + k*256;
    const int cl = e / CIST;
    const int rem = e - cl*CIST;
    const int r  = rem / ROWW;
    const int j  = rem - r*ROWW;
    const int yg = y0 - 1 + r, xg = x0 - 1 + j;
    soff[k] = (e < CHFL && yg>=0 && yg<H && xg>=0 && xg<W)
            ? (cl*H + yg)*W + xg : -1;
  }

  // load + immediately store to LDS (short live ranges -> no spill)
#define STAGE(CB, BUF) do {                                                  \
    const float* Fb_ = Fn + (size_t)(CB)*H*W;                                \
    float st_[NSTG];                                                         \
    _Pragma("unroll")                                                        \
    for (int k=0;k<NSTG;k++)                                                 \
      st_[k] = (soff[k] >= 0) ? Fb_[soff[k]] : 0.f;                          \
    _Pragma("unroll")                                                        \
    for (int k=0;k<NSTG;k++){                                                \
      const int e = co + k*256;                                              \
      if (e < CHFL) (BUF)[e] = st_[k];                                       \
    }                                                                        \
  } while(0)

  // compile-time component select (folds to a direct register reference)
#define CMP4_(Q,I) ((I)==0?(Q).x:((I)==1?(Q).y:((I)==2?(Q).z:(Q).w)))
#define EL_(I) ((I)<4 ? CMP4_(q0_,(I)) : ((I)<8 ? CMP4_(q1_,(I)-4) : CMP4_(q2_,(I)-8)))

  // one ci: 4 input rows; row r -> acc[0](ky=r) and acc[1](ky=r-1)
#define CIFMA(SB, CL, WV) do {                                               \
    const float* bp_ = (SB) + (CL)*CIST;                                     \
    _Pragma("unroll")                                                        \
    for (int r=0;r<4;r++){                                                   \
      float4 q0_ = *(const float4*)(bp_ + r*ROWW);                           \
      float4 q1_ = *(const float4*)(bp_ + r*ROWW + 4);                       \
      float4 q2_ = (ROWW > 8) ? *(const float4*)(bp_ + r*ROWW + 8)           \
                              : make_float4(0.f,0.f,0.f,0.f);                \
      if (r <= 2){                                                           \
        _Pragma("unroll")                                                    \
        for (int kx=0;kx<3;kx++){                                            \
          const float w_ = WV[r*3+kx];                                       \
          _Pragma("unroll")                                                  \
          for (int p=0;p<TX;p++) acc[0][p] = fmaf(w_, EL_(p+kx), acc[0][p]); \
        }                                                                    \
      }                                                                      \
      if (r >= 1){                                                           \
        _Pragma("unroll")                                                    \
        for (int kx=0;kx<3;kx++){                                            \
          const float w_ = WV[(r-1)*3+kx];                                   \
          _Pragma("unroll")                                                  \
          for (int p=0;p<TX;p++) acc[1][p] = fmaf(w_, EL_(p+kx), acc[1][p]); \
        }                                                                    \
      }                                                                      \
    }                                                                        \
  } while(0)

  STAGE(0, lds_stage);
  __syncthreads();

  for (int ch=0; ch<8; ++ch){
    const float* sb = lds_stage + (ch&1)*CHBUF;
    for (int cl=0; cl<32; ++cl){
      const int ci = ch*32 + cl;
      float wv[9];
      const float* wrow = wp + (size_t)ci*2304 + co;
      #pragma unroll
      for (int t=0;t<9;t++) wv[t] = wrow[t*256];
      CIFMA(sb, cl, wv);
    }
    if (ch<7){
      STAGE((ch+1)*32, lds_stage + ((ch+1)&1)*CHBUF);
      __syncthreads();
    }
  }
#undef STAGE
#undef CIFMA
#undef EL_
#undef CMP4_

  // guard: all waves done reading stage before lds_t overwrites it
  __syncthreads();

  // t tile -> LDS (stride 260: float4-aligned, 2-way-max banks)
  #pragma unroll
  for (int o=0;o<2;o++)
    #pragma unroll
    for (int p=0;p<TX;p++) lds_t[(o*TX+p)*260+co] = fmaxf(acc[o][p], 0.f);
  __syncthreads();

  {
    const int p = threadIdx.x % P;
    const int o = threadIdx.x / P;
    if (o < 15){
      const float* w1 = (o<3) ? (cls_w + o*256) : (bbox_w + (o-3)*256);
      float s = (o<3) ? cls_b[o] : bbox_b[o-3];
      const float4* wl = (const float4*)w1;
      const float4* tl = (const float4*)(lds_t + p*260);
      #pragma unroll 8
      for (int c=0;c<64;c++){
        float4 a = wl[c], b = tl[c];
        s += a.x*b.x + a.y*b.y + a.z*b.z + a.w*b.w;
      }
      s_out[o][p] = s;
    }
  }
  __syncthreads();

  if (threadIdx.x < 3*P){
    const int p = threadIdx.x / 3;
    const int a = threadIdx.x % 3;
    const int px = p % TX;
    const int yo = y0 + p / TX;
    float sraw = s_out[a][p];
    float dx = s_out[3+a*4+0][p];
    float dy = s_out[3+a*4+1][p];
    float dw = fminf(s_out[3+a*4+2][p], BBOX_CLIP);
    float dh = fminf(s_out[3+a*4+3][p], BBOX_CLIP);
    float ratio = (a==0)?0.5f:((a==1)?1.0f:2.0f);
    float hr = sqrtf(ratio);
    float wh2 = rintf(asize / hr * 0.5f);   // round-half-even == np.round (no .5 cases)
    float hh2 = rintf(asize * hr * 0.5f);
    float w = 2.f*wh2, h = 2.f*hh2;
    float cx = (float)((x0+px)*strd);
    float cy = (float)(yo*strd);
    float pcx = dx*w + cx, pcy = dy*h + cy;
    float pw = expf(dw)*w, ph = expf(dh)*h;
    float x1 = pcx - 0.5f*pw, y1 = pcy - 0.5f*ph;
    float x2 = pcx + 0.5f*pw, y2 = pcy + 0.5f*ph;
    x1 = fminf(fmaxf(x1,0.f),512.f); y1 = fminf(fmaxf(y1,0.f),512.f);
    x2 = fminf(fmaxf(x2,0.f),512.f); y2 = fminf(fmaxf(y2,0.f),512.f);
    bool valid = ((x2-x1) >= 1e-3f) && ((y2-y1) >= 1e-3f);
    float prob = 1.f/(1.f+expf(-sraw));
    float masked = valid ? prob : -1.f;
    float off = lvl*513.f;
    size_t gi = (size_t)n*FULL_PER_IMG + full_off + ((yo*W + (x0+px))*3 + a);
    A_score[gi]  = sraw;
    A_masked[gi] = masked;
    float4 bo; bo.x=x1+off; bo.y=y1+off; bo.z=x2+off; bo.w=y2+off;
    *(float4*)(A_boxoff + gi*4) = bo;
  }
}

// All 5 levels in ONE dispatch: 4096+1024+256+128+32 = 5536 blocks.
__global__ __launch_bounds__(256)
void conv_all(
    const float* __restrict__ f0, const float* __restrict__ f1,
    const float* __restrict__ f2, const float* __restrict__ f3,
    const float* __restrict__ f4,
    const float* __restrict__ wp, const float* __restrict__ conv_b,
    const float* __restrict__ cls_w, const float* __restrict__ cls_b,
    const float* __restrict__ bbox_w, const float* __restrict__ bbox_b,
    float* __restrict__ A_score, float* __restrict__ A_masked, float* __restrict__ A_boxoff)
{
  __shared__ float smem[SMEMF];
  __shared__ float s_out[15][16];
  const int b = blockIdx.x;
  if (b < 4096)
    conv_level< 8,128,16>(b,      f0,  4,  16.f,     0, 0.f, wp, conv_b, cls_w, cls_b, bbox_w, bbox_b, A_score, A_masked, A_boxoff, smem, s_out);
  else if (b < 5120)
    conv_level< 8, 64, 8>(b-4096, f1,  8,  32.f, 49152, 1.f, wp, conv_b, cls_w, cls_b, bbox_w, bbox_b, A_score, A_masked, A_boxoff, smem, s_out);
  else if (b < 5376)
    conv_level< 8, 32, 4>(b-5120, f2, 16,  64.f, 61440, 2.f, wp, conv_b, cls_w, cls_b, bbox_w, bbox_b, A_score, A_masked, A_boxoff, smem, s_out);
  else if (b < 5504)
    conv_level< 4, 16, 4>(b-5376, f3, 32, 128.f, 64512, 3.f, wp, conv_b, cls_w, cls_b, bbox_w, bbox_b, A_score, A_masked, A_boxoff, smem, s_out);
  else
    conv_level< 4,  8, 2>(b-5504, f4, 64, 256.f, 65280, 4.f, wp, conv_b, cls_w, cls_b, bbox_w, bbox_b, A_score, A_masked, A_boxoff, smem, s_out);
}

// blocks 0..11: exact top-1000 radix select per (img, lvl 0..2)
//   per-wave sub-histograms + float4-vectorized score scans.
// blocks 12..15: lvl3+lvl4 passthrough copy (one block per image)
__global__ __launch_bounds__(1024) void select_kernel(
    const float* __restrict__ A_score, const float* __restrict__ A_masked,
    const float* __restrict__ A_boxoff,
    float* __restrict__ C_masked, float* __restrict__ C_boxoff)
{
  const int b = blockIdx.x;
  const int tid = threadIdx.x;
  if (b >= 12){
    const int n = b - 12;
    if (tid < 240){
      size_t gF = (size_t)n*FULL_PER_IMG + 64512 + tid*4;
      size_t gS = (size_t)n*SEL_PER_IMG  + 3000 + tid*4;
      *(float4*)(C_masked + gS) = *(const float4*)(A_masked + gF);
    }
    if (tid < 960){
      size_t gF = (size_t)n*FULL_PER_IMG + 64512 + tid;
      size_t gS = (size_t)n*SEL_PER_IMG  + 3000 + tid;
      *(float4*)(C_boxoff + gS*4) = *(const float4*)(A_boxoff + gF*4);
    }
    return;
  }
  const int n = b / 3, lvl = b % 3;
  const int HWAs[3]  = {49152, 12288, 3072};
  const int FOFF[3]  = {0, 49152, 61440};
  const int HWA = HWAs[lvl];
  const size_t baseF = (size_t)n*FULL_PER_IMG + FOFF[lvl];
  const size_t baseS = (size_t)n*SEL_PER_IMG + lvl*1000;
  const int k = 1000;
  const int wid = tid >> 6;      // 16 waves

  __shared__ unsigned int hist[16][256];
  __shared__ unsigned int histM[256];
  __shared__ unsigned int sh_prefix, sh_krem, sh_c0, sh_c1, sh_above;
  if (tid==0){ sh_prefix=0u; sh_krem=(unsigned)k; }
  __syncthreads();

  for (int pass=3; pass>=0; pass--){
    unsigned int* hp = &hist[0][0];
    for (int z=tid; z<4096; z+=1024) hp[z] = 0u;
    __syncthreads();
    unsigned int pfx = sh_prefix;
    for (int i4=tid; i4<(HWA>>2); i4+=1024){
      float4 sc = *(const float4*)(A_score + baseF + (size_t)i4*4);
      #pragma unroll
      for (int j=0;j<4;j++){
        float sv = (j==0)?sc.x:((j==1)?sc.y:((j==2)?sc.z:sc.w));
        unsigned int u = sortkey(sv);
        if (pass==3 || (u >> ((pass+1)*8)) == pfx)
          atomicAdd(&hist[wid][(u>>(pass*8)) & 255u], 1u);
      }
    }
    __syncthreads();
    if (tid < 256){
      unsigned int s = 0u;
      #pragma unroll
      for (int w=0;w<16;w++) s += hist[w][tid];
      histM[tid] = s;
    }
    __syncthreads();
    if (tid==0){
      unsigned int krem = sh_krem, accum = 0u; int chosen = 0;
      for (int bb=255; bb>=0; bb--){
        if (accum + histM[bb] >= krem){ chosen = bb; break; }
        accum += histM[bb];
      }
      sh_krem   = krem - accum;
      sh_prefix = (pfx<<8) | (unsigned)chosen;
    }
    __syncthreads();
  }
  const unsigned int T = sh_prefix;
  if (tid==0){ sh_c0=0u; sh_c1=0u; sh_above = (unsigned)k - sh_krem; }
  __syncthreads();
  const unsigned int nAbove = sh_above, need = sh_krem;

  for (int i4=tid; i4<(HWA>>2); i4+=1024){
    float4 sc = *(const float4*)(A_score + baseF + (size_t)i4*4);
    #pragma unroll
    for (int j=0;j<4;j++){
      float sv = (j==0)?sc.x:((j==1)?sc.y:((j==2)?sc.z:sc.w));
      unsigned int u = sortkey(sv);
      int i = i4*4 + j;
      int pos = -1;
      if (u > T) pos = (int)atomicAdd(&sh_c0,1u);
      else if (u == T){
        unsigned int t = atomicAdd(&sh_c1,1u);
        if (t < need) pos = (int)(nAbove + t);
      }
      if (pos >= 0){
        C_masked[baseS+pos] = A_masked[baseF+i];
        *(float4*)(C_boxoff + (baseS+pos)*4) = *(const float4*)(A_boxoff + (baseF+i)*4);
      }
    }
  }
}

// NMS sort-then-scan (== greedy argmax-NMS):
// 1) bitonic sort 4096 keys (score desc, idx asc);
// 2) top-1024 boxes cached in LDS; single-wave scan with next-iter prefetch.
__global__ __launch_bounds__(256) void nms_kernel(
    const float* __restrict__ C_masked, const float* __restrict__ C_boxoff,
    float* __restrict__ out_b, float* __restrict__ out_s)
{
  const int n = blockIdx.x, tid = threadIdx.x;
  __shared__ unsigned long long keys[4096];
  __shared__ float4 bcache[1024];
  __shared__ float accb[304][4];

  // fill: key = sortkey(masked)<<32 | ~idx  (desc score, asc idx on tie)
  #pragma unroll
  for (int s=0; s<16; ++s){
    int i = s*256 + tid;
    unsigned long long kk = 0ull;
    if (i < SEL_PER_IMG){
      unsigned int sk = sortkey(C_masked[(size_t)n*SEL_PER_IMG + i]);
      kk = ((unsigned long long)sk << 32) | (unsigned int)(~(unsigned int)i);
    }
    keys[i] = kk;
  }
  __syncthreads();

  // bitonic sort, descending
  for (int k = 2; k <= 4096; k <<= 1){
    for (int j = k >> 1; j > 0; j >>= 1){
      #pragma unroll
      for (int s=0; s<16; ++s){
        int i = s*256 + tid;
        int ixj = i ^ j;
        if (ixj > i){
          unsigned long long a = keys[i], b = keys[ixj];
          bool up = ((i & k) == 0);
          bool sw = up ? (a < b) : (a > b);
          if (sw){ keys[i] = b; keys[ixj] = a; }
        }
      }
      __syncthreads();
    }
  }

  // cache boxes for the top 1024 sorted slots (all are real candidates)
  for (int s=tid; s<1024; s+=256){
    int idx = (int)(~(unsigned int)keys[s]);
    bcache[s] = *(const float4*)(C_boxoff + ((size_t)n*SEL_PER_IMG + idx)*4);
  }
  __syncthreads();

  if (tid >= 64) return;        // single-wave scan, no more barriers
  const unsigned int THRK = sortkey(-0.5f);   // accept requires khi > this
  int nAcc = 0;
  unsigned long long kk = keys[0];
  float4 bx = bcache[0];
  for (int i = 0; i < 4096 && nAcc < 300; ++i){
    // prefetch next candidate (key + box) before this iteration's work
    unsigned long long kn = (i+1 < 4096) ? keys[i+1] : 0ull;
    unsigned int khin = (unsigned int)(kn >> 32);
    float4 bnext = make_float4(0.f,0.f,0.f,0.f);
    if (i+1 < 1024) bnext = bcache[i+1];
    else if (khin > THRK){
      int idn = (int)(~(unsigned int)kn);
      bnext = *(const float4*)(C_boxoff + ((size_t)n*SEL_PER_IMG + idn)*4);
    }
    unsigned int khi = (unsigned int)(kk >> 32);
    if (khi <= THRK) break;                    // score <= -0.5: rest are too
    bool sup = false;
    #pragma unroll
    for (int q=0; q<5; ++q){
      int a = tid + q*64;
      if (a < nAcc){
        float a0=accb[a][0], a1=accb[a][1], a2=accb[a][2], a3=accb[a][3];
        float xx1 = fmaxf(a0, bx.x), yy1 = fmaxf(a1, bx.y);
        float xx2 = fminf(a2, bx.z), yy2 = fminf(a3, bx.w);
        float iw = fmaxf(xx2-xx1, 0.f), ih = fmaxf(yy2-yy1, 0.f);
        float inter = iw*ih;
        float ar_a = (a2-a0)*(a3-a1);
        float ar_b = (bx.z-bx.x)*(bx.w-bx.y);
        float iou = inter / fmaxf(ar_a + ar_b - inter, 1e-9f);
        sup |= (iou > 0.7f);
      }
    }
    if (__ballot(sup) == 0ull){
      if (tid == 0){
        accb[nAcc][0]=bx.x; accb[nAcc][1]=bx.y; accb[nAcc][2]=bx.z; accb[nAcc][3]=bx.w;
        int idx = (int)(~(unsigned int)kk);
        int lvl = (idx<1000)?0:((idx<2000)?1:((idx<3000)?2:((idx<3768)?3:4)));
        float off = (float)lvl * 513.f;
        size_t ob = ((size_t)n*300 + nAcc)*4;
        out_b[ob+0]=bx.x-off; out_b[ob+1]=bx.y-off; out_b[ob+2]=bx.z-off; out_b[ob+3]=bx.w-off;
        out_s[(size_t)n*300 + nAcc] = __uint_as_float(khi & 0x7fffffffu); // prob >= 0: sortkey inverse
      }
      ++nAcc;
    }
    kk = kn; bx = bnext;
  }
}

extern "C" void kernel_launch(void* const* d_in, const int* in_sizes, int n_in,
                              void* d_out, int out_size, void* d_ws, size_t ws_size,
                              hipStream_t stream) {
  (void)in_sizes; (void)n_in; (void)ws_size;
  const float* f0     = (const float*)d_in[1];
  const float* f1     = (const float*)d_in[2];
  const float* f2     = (const float*)d_in[3];
  const float* f3     = (const float*)d_in[4];
  const float* f4     = (const float*)d_in[5];
  const float* conv_w = (const float*)d_in[6];
  const float* conv_b = (const float*)d_in[7];
  const float* cls_w  = (const float*)d_in[8];
  const float* cls_b  = (const float*)d_in[9];
  const float* bbox_w = (const float*)d_in[10];
  const float* bbox_b = (const float*)d_in[11];

  float* ws       = (float*)d_ws;
  float* wp       = ws;                       // 589824 ([ci][tap][co])
  float* A_score  = wp       + 589824;        // 261888
  float* A_masked = A_score  + 261888;        // 261888
  float* A_boxoff = A_masked + 261888;        // 1047552
  float* C_masked = A_boxoff + 1047552;       // 15840
  float* C_boxoff = C_masked + 15840;         // 63360

  float* out_b = (float*)d_out;               // [4][300][4]
  float* out_s = out_b + 4800;                // [4][300]

  hipMemsetAsync(d_out, 0, (size_t)out_size*sizeof(float), stream);

  repack_w<<<256, 256, 0, stream>>>(conv_w, wp);

  conv_all<<<5536, 256, 0, stream>>>(f0, f1, f2, f3, f4,
      wp, conv_b, cls_w, cls_b, bbox_w, bbox_b, A_score, A_masked, A_boxoff);

  select_kernel<<<16, 1024, 0, stream>>>(A_score, A_masked, A_boxoff, C_masked, C_boxoff);
  nms_kernel<<<4, 256, 0, stream>>>(C_masked, C_boxoff, out_b, out_s);
}